// Round 8
// baseline (344.811 us; speedup 1.0000x reference)
//
#include <hip/hip_runtime.h>
#include <cmath>

constexpr int B = 2, L = 4096, D = 256, H = 8, NC = 3;
constexpr int TOP_N = 8, R = 32;
constexpr int LS = 1000, LE = 3000;
constexpr int NL = 2;
constexpr int FF = 4 * D;                        // 1024
constexpr int Q_MAX = 2 * TOP_N * (2 * R + 1);   // 1040
constexpr int HD = D / H;                        // 32
constexpr int QROWS = B * Q_MAX;                 // 2080
constexpr int KVROWS = B * L;                    // 8192
constexpr int NQT = (Q_MAX + 31) / 32;           // 33 q-tiles of 32
constexpr int NREG = LE - LS;                    // 2000
constexpr int NSPLIT = 4;                        // split-K waves per block
constexpr int KCHUNK = L / NSPLIT;               // 1024 keys per wave
constexpr int NT = KCHUNK / 32;                  // 32 iterations

typedef __attribute__((ext_vector_type(8))) short bf16x8;
typedef __attribute__((ext_vector_type(4))) float f32x4;
typedef __attribute__((ext_vector_type(4))) int i32x4;
typedef unsigned short u16;

union fr {
  bf16x8 h;
  i32x4 i;
};

__device__ __forceinline__ u16 f2bs(float f) {
  unsigned int u = __float_as_uint(f);
  unsigned int r = u + 0x7fffu + ((u >> 16) & 1u);
  return (u16)(r >> 16);
}
__device__ __forceinline__ float bs2f(u16 s) {
  return __uint_as_float(((unsigned int)s) << 16);
}
__device__ __forceinline__ float gelu_exact(float x) {
  return 0.5f * x * (1.f + erff(x * 0.70710678118654752440f));
}
__device__ __forceinline__ unsigned cvt_pk(float lo, float hi) {
  unsigned r;
  asm("v_cvt_pk_bf16_f32 %0, %1, %2" : "=v"(r) : "v"(lo), "v"(hi));
  return r;
}

#define GLL16(gsrc, ldst)                                                   \
  __builtin_amdgcn_global_load_lds(                                         \
      (const __attribute__((address_space(1))) unsigned int*)(gsrc),        \
      (__attribute__((address_space(3))) unsigned int*)(ldst), 16, 0, 0)

// ---------------------------------------------------------------------------
// Vicinity selection. One 1024-thread block per batch.
// ---------------------------------------------------------------------------
__global__ __launch_bounds__(1024) void select_kernel(
    const float* __restrict__ logits, int* __restrict__ idx_out,
    int* __restrict__ mask_out) {
  int b = blockIdx.x;
  int tid = threadIdx.x;
  __shared__ float vv[2][NREG];
  __shared__ int centers[2 * TOP_N];
  __shared__ unsigned present[L / 32];
  __shared__ float wred[16];
  __shared__ int wredi[16];
  __shared__ int offs[128];
  __shared__ int wtot[2];

  for (int p = tid; p < NREG; p += 1024) {
    const float* lg = logits + ((long)b * L + LS + p) * NC;
    float x0 = lg[0], x1 = lg[1], x2 = lg[2];
    float m = fmaxf(x0, fmaxf(x1, x2));
    float lse = m + logf(expf(x0 - m) + expf(x1 - m) + expf(x2 - m));
    vv[0][p] = x2 - lse;  // don
    vv[1][p] = x1 - lse;  // acc
  }
  if (tid < 128) present[tid] = 0;
  __syncthreads();

  for (int sel = 0; sel < 2; ++sel) {
    for (int t = 0; t < TOP_N; ++t) {
      float bv = -INFINITY;
      int bi = 0x7fffffff;
      for (int p = tid; p < NREG; p += 1024) {
        float x = vv[sel][p];
        if (x > bv || (x == bv && p < bi)) { bv = x; bi = p; }
      }
#pragma unroll
      for (int off = 32; off; off >>= 1) {
        float ov = __shfl_xor(bv, off, 64);
        int oi = __shfl_xor(bi, off, 64);
        if (ov > bv || (ov == bv && oi < bi)) { bv = ov; bi = oi; }
      }
      if ((tid & 63) == 0) { wred[tid >> 6] = bv; wredi[tid >> 6] = bi; }
      __syncthreads();
      if (tid < 64) {
        bv = (tid < 16) ? wred[tid] : -INFINITY;
        bi = (tid < 16) ? wredi[tid] : 0x7fffffff;
#pragma unroll
        for (int off = 8; off; off >>= 1) {
          float ov = __shfl_xor(bv, off, 64);
          int oi = __shfl_xor(bi, off, 64);
          if (ov > bv || (ov == bv && oi < bi)) { bv = ov; bi = oi; }
        }
        if (tid == 0) {
          centers[sel * TOP_N + t] = LS + bi;
          vv[sel][bi] = -INFINITY;
        }
      }
      __syncthreads();
    }
  }

  for (int j = tid; j < Q_MAX; j += 1024) {
    int c = centers[j / (2 * R + 1)];
    int off = j % (2 * R + 1) - R;
    int v = c + off;
    v = v < 0 ? 0 : (v > L - 1 ? L - 1 : v);
    atomicOr(&present[v >> 5], 1u << (v & 31));
  }
  __syncthreads();

  int cnt = (tid < 128) ? __popc(present[tid]) : 0;
  if (tid < 128) {
    int x = cnt;
#pragma unroll
    for (int off = 1; off < 64; off <<= 1) {
      int o = __shfl_up(x, off, 64);
      if ((tid & 63) >= off) x += o;
    }
    if ((tid & 63) == 63) wtot[tid >> 6] = x;
    offs[tid] = x - cnt;
  }
  __syncthreads();
  int total = wtot[0] + wtot[1];
  if (tid < 128) {
    int base = offs[tid] + ((tid >= 64) ? wtot[0] : 0);
    unsigned mword = present[tid];
    while (mword) {
      int i = __ffs(mword) - 1;
      mword &= mword - 1;
      idx_out[b * Q_MAX + base] = tid * 32 + i;
      mask_out[b * Q_MAX + base] = 1;
      ++base;
    }
  }
  for (int j = total + tid; j < Q_MAX; j += 1024) {
    idx_out[b * Q_MAX + j] = L;
    mask_out[b * Q_MAX + j] = 0;
  }
}

// ---------------------------------------------------------------------------
__global__ __launch_bounds__(256) void gather_kernel(
    const float* __restrict__ enc, const int* __restrict__ idx,
    float* __restrict__ q_stream) {
  int row = blockIdx.x;
  int b = row / Q_MAX;
  int p = idx[row];
  float v = 0.f;
  if (p < L) v = enc[((long)b * L + p) * D + threadIdx.x];
  q_stream[(long)row * D + threadIdx.x] = v;
}

// ---------------------------------------------------------------------------
__global__ __launch_bounds__(256) void transpose_all(
    const float* __restrict__ Wq_, const float* __restrict__ Wk_,
    const float* __restrict__ Wv_, const float* __restrict__ Wo_,
    const float* __restrict__ W1_, const float* __restrict__ W2_,
    u16* __restrict__ WT) {
  const long DD = (long)D * D, DFF = (long)D * FF;
  const long LSTR = 4 * DD + 2 * DFF;
  long t = (long)blockIdx.x * 256 + threadIdx.x;
  if (t >= NL * LSTR) return;
  int l = (int)(t / LSTR);
  long r = t - (long)l * LSTR;
  const float* src;
  long dstbase, e;
  int K_, N_;
  if (r < 4 * DD) {
    int which = (int)(r >> 16);
    e = r & (DD - 1);
    K_ = D; N_ = D;
    src = (which == 0 ? Wk_ : which == 1 ? Wv_ : which == 2 ? Wq_ : Wo_) +
          (long)l * DD;
    dstbase = l * LSTR + which * DD;
  } else if (r < 4 * DD + DFF) {
    e = r - 4 * DD;
    K_ = D; N_ = FF;
    src = W1_ + (long)l * DFF;
    dstbase = l * LSTR + 4 * DD;
  } else {
    e = r - 4 * DD - DFF;
    K_ = FF; N_ = D;
    src = W2_ + (long)l * DFF;
    dstbase = l * LSTR + 4 * DD + DFF;
  }
  int k = (int)(e / N_), n = (int)(e % N_);
  WT[dstbase + (long)n * K_ + k] = f2bs(src[e]);
}

// ---------------------------------------------------------------------------
// bf16 MFMA GEMM (64x64 tile, BK=32, 4 waves), bf16 A input.
// EPI 2: resid+mask->f32 (used for O-proj and FFN-2)
// ---------------------------------------------------------------------------
template <int EPI>
__global__ __launch_bounds__(256) void gemm_mfma(
    const u16* __restrict__ A, const u16* __restrict__ BT,
    const float* __restrict__ bias, void* __restrict__ Cv,
    const float* __restrict__ resid, const int* __restrict__ mask, int M,
    int N, int K) {
  __shared__ short As[64][40];
  __shared__ short Bs[64][40];
  int bm = blockIdx.y * 64, bn = blockIdx.x * 64;
  int tid = threadIdx.x;
  int lane = tid & 63, w = tid >> 6;
  int g = lane >> 4, li = lane & 15;
  int wr = w >> 1, wc = w & 1;
  f32x4 acc[2][2] = {};

  int srow = tid >> 2, skc = (tid & 3) * 8;
  for (int k0 = 0; k0 < K; k0 += 32) {
    {
      int grow = bm + srow;
      bf16x8 av = {};
      if (grow < M)
        av = *reinterpret_cast<const bf16x8*>(A + (long)grow * K + k0 + skc);
      *reinterpret_cast<bf16x8*>(&As[srow][skc]) = av;
      bf16x8 bv = *reinterpret_cast<const bf16x8*>(
          BT + (long)(bn + srow) * K + k0 + skc);
      *reinterpret_cast<bf16x8*>(&Bs[srow][skc]) = bv;
    }
    __syncthreads();
    bf16x8 a0 = *reinterpret_cast<const bf16x8*>(&As[wr * 32 + li][g * 8]);
    bf16x8 a1 = *reinterpret_cast<const bf16x8*>(&As[wr * 32 + 16 + li][g * 8]);
    bf16x8 b0 = *reinterpret_cast<const bf16x8*>(&Bs[wc * 32 + li][g * 8]);
    bf16x8 b1 = *reinterpret_cast<const bf16x8*>(&Bs[wc * 32 + 16 + li][g * 8]);
    acc[0][0] = __builtin_amdgcn_mfma_f32_16x16x32_bf16(a0, b0, acc[0][0], 0, 0, 0);
    acc[0][1] = __builtin_amdgcn_mfma_f32_16x16x32_bf16(a0, b1, acc[0][1], 0, 0, 0);
    acc[1][0] = __builtin_amdgcn_mfma_f32_16x16x32_bf16(a1, b0, acc[1][0], 0, 0, 0);
    acc[1][1] = __builtin_amdgcn_mfma_f32_16x16x32_bf16(a1, b1, acc[1][1], 0, 0, 0);
    __syncthreads();
  }

#pragma unroll
  for (int mr = 0; mr < 2; ++mr)
#pragma unroll
    for (int nr = 0; nr < 2; ++nr)
#pragma unroll
      for (int r = 0; r < 4; ++r) {
        int row = bm + wr * 32 + mr * 16 + g * 4 + r;
        int col = bn + wc * 32 + nr * 16 + li;
        if (row >= M) continue;
        float v = acc[mr][nr][r] + bias[col];
        if (EPI == 1) v = gelu_exact(v);
        if (EPI == 2) {
          v += resid[(long)row * N + col];
          v = mask[row] ? v : 0.f;
          ((float*)Cv)[(long)row * N + col] = v;
        } else {
          ((u16*)Cv)[(long)row * N + col] = f2bs(v);
        }
      }
}

// ---------------------------------------------------------------------------
// LN-fused bf16 MFMA GEMM: A fp32 [M][256], LayerNorm applied during A-tile
// staging (full LN'd A-tile resident in LDS; K=256 fixed).
// EPI 0: (bias)*QSC -> bf16 (Q proj, pre-scaled for exp2 softmax)
// EPI 1: gelu(bias+x) -> bf16 (FFN-1, N=FF)
// EPI 2: K/V dual epilogue (R6-proven, unswizzled):
//   bn<256  -> Kh[b][h][key][d]             (64B contiguous key rows)
//   bn>=256 -> Vh[b][h][key/32][d][key%32]  (32-key contiguous tiles)
// ---------------------------------------------------------------------------
template <int EPI>
__global__ __launch_bounds__(256) void gemm_ln(
    const float* __restrict__ A, const u16* __restrict__ BT,
    const float* __restrict__ lng, const float* __restrict__ lnb,
    const float* __restrict__ bias, const float* __restrict__ biasV,
    u16* __restrict__ C, u16* __restrict__ C2, int M) {
  __shared__ u16 As[64][264];
  __shared__ u16 Bs[64][40];
  int bm = blockIdx.y * 64, bn = blockIdx.x * 64;
  int tid = threadIdx.x;
  int lane = tid & 63, w = tid >> 6;
  int g = lane >> 4, li = lane & 15;
  int wr = w >> 1, wc = w & 1;

  // ---- LN-staged A tile (4 threads per row; row clamped to M-1)
  {
    int r = tid >> 2, qd = tid & 3;
    int grow = bm + r;
    if (grow >= M) grow = M - 1;
    const float* ap = A + ((long)grow) * D + qd * 64;
    float sum = 0.f, ss = 0.f;
#pragma unroll
    for (int i = 0; i < 16; ++i) {
      float4 v = *reinterpret_cast<const float4*>(ap + i * 4);
      sum += v.x + v.y + v.z + v.w;
      ss += v.x * v.x + v.y * v.y + v.z * v.z + v.w * v.w;
    }
    sum += __shfl_xor(sum, 1, 64);
    sum += __shfl_xor(sum, 2, 64);
    ss += __shfl_xor(ss, 1, 64);
    ss += __shfl_xor(ss, 2, 64);
    float mean = sum * (1.f / D);
    float var = fmaxf(ss * (1.f / D) - mean * mean, 0.f);
    float rstd = rsqrtf(var + 1e-5f);
#pragma unroll
    for (int i = 0; i < 8; ++i) {
      int k = qd * 64 + i * 8;
      float4 xa = *reinterpret_cast<const float4*>(ap + i * 8);
      float4 xb = *reinterpret_cast<const float4*>(ap + i * 8 + 4);
      float4 ga = *reinterpret_cast<const float4*>(lng + k);
      float4 gb = *reinterpret_cast<const float4*>(lng + k + 4);
      float4 ba = *reinterpret_cast<const float4*>(lnb + k);
      float4 bb = *reinterpret_cast<const float4*>(lnb + k + 4);
      fr v;
      v.i[0] = (int)cvt_pk((xa.x - mean) * rstd * ga.x + ba.x,
                           (xa.y - mean) * rstd * ga.y + ba.y);
      v.i[1] = (int)cvt_pk((xa.z - mean) * rstd * ga.z + ba.z,
                           (xa.w - mean) * rstd * ga.w + ba.w);
      v.i[2] = (int)cvt_pk((xb.x - mean) * rstd * gb.x + bb.x,
                           (xb.y - mean) * rstd * gb.y + bb.y);
      v.i[3] = (int)cvt_pk((xb.z - mean) * rstd * gb.z + bb.z,
                           (xb.w - mean) * rstd * gb.w + bb.w);
      *reinterpret_cast<bf16x8*>(&As[r][k]) = v.h;
    }
  }
  __syncthreads();

  f32x4 acc[2][2] = {};
  int srow = tid >> 2, skc = (tid & 3) * 8;
  for (int k0 = 0; k0 < D; k0 += 32) {
    *reinterpret_cast<bf16x8*>(&Bs[srow][skc]) =
        *reinterpret_cast<const bf16x8*>(BT + (long)(bn + srow) * D + k0 + skc);
    __syncthreads();
    bf16x8 a0 = *reinterpret_cast<const bf16x8*>(&As[wr * 32 + li][k0 + g * 8]);
    bf16x8 a1 =
        *reinterpret_cast<const bf16x8*>(&As[wr * 32 + 16 + li][k0 + g * 8]);
    bf16x8 b0 = *reinterpret_cast<const bf16x8*>(&Bs[wc * 32 + li][g * 8]);
    bf16x8 b1 = *reinterpret_cast<const bf16x8*>(&Bs[wc * 32 + 16 + li][g * 8]);
    acc[0][0] = __builtin_amdgcn_mfma_f32_16x16x32_bf16(a0, b0, acc[0][0], 0, 0, 0);
    acc[0][1] = __builtin_amdgcn_mfma_f32_16x16x32_bf16(a0, b1, acc[0][1], 0, 0, 0);
    acc[1][0] = __builtin_amdgcn_mfma_f32_16x16x32_bf16(a1, b0, acc[1][0], 0, 0, 0);
    acc[1][1] = __builtin_amdgcn_mfma_f32_16x16x32_bf16(a1, b1, acc[1][1], 0, 0, 0);
    __syncthreads();
  }

  if constexpr (EPI == 2) {
    __shared__ u16 Ct[64][72];
    if (bn < 256) {
      // K epilogue: Kh[b][h][key][d] (64B contiguous key rows)
#pragma unroll
      for (int mr = 0; mr < 2; ++mr)
#pragma unroll
        for (int nr = 0; nr < 2; ++nr)
#pragma unroll
          for (int r = 0; r < 4; ++r) {
            int rowL = wr * 32 + mr * 16 + g * 4 + r;
            int colL = wc * 32 + nr * 16 + li;
            Ct[rowL][colL] = f2bs(acc[mr][nr][r] + bias[bn + colL]);
          }
      __syncthreads();
#pragma unroll
      for (int p = 0; p < 2; ++p) {
        int rowL = (tid >> 3) + p * 32;
        int c8 = (tid & 7) * 8;
        int grow = bm + rowL;
        int b2 = grow >> 12, key = grow & (L - 1);
        int gcol = bn + c8;
        int hh = gcol >> 5, dd = gcol & (HD - 1);
        u16* dst = C + (((long)(b2 * H + hh) * L + key) * 32 + dd);
        *reinterpret_cast<bf16x8*>(dst) =
            *reinterpret_cast<const bf16x8*>(&Ct[rowL][c8]);
      }
    } else {
      // V epilogue: Vh[b][h][key/32][d][key%32]
      int vbn = bn - 256;
#pragma unroll
      for (int mr = 0; mr < 2; ++mr)
#pragma unroll
        for (int nr = 0; nr < 2; ++nr)
#pragma unroll
          for (int r = 0; r < 4; ++r) {
            int rowL = wr * 32 + mr * 16 + g * 4 + r;
            int colL = wc * 32 + nr * 16 + li;
            Ct[colL][rowL] = f2bs(acc[mr][nr][r] + biasV[vbn + colL]);
          }
      __syncthreads();
      int b2 = bm >> 12;
#pragma unroll
      for (int p = 0; p < 2; ++p) {
        int colL = (tid >> 3) + p * 32;
        int rem = tid & 7;
        int kb = rem >> 2, k8 = (rem & 3) * 8;
        int gcol = vbn + colL;
        int hh = gcol >> 5, dd = gcol & (HD - 1);
        int kb32 = ((bm & (L - 1)) >> 5) + kb;
        u16* dst = C2 + (((long)(b2 * H + hh) * (L / 32) + kb32) * 1024 +
                         dd * 32 + k8);
        *reinterpret_cast<bf16x8*>(dst) =
            *reinterpret_cast<const bf16x8*>(&Ct[colL][kb * 32 + k8]);
      }
    }
  } else {
    const float QSC = 0.25509836048f;  // (1/sqrt(32)) * log2(e)
#pragma unroll
    for (int mr = 0; mr < 2; ++mr)
#pragma unroll
      for (int nr = 0; nr < 2; ++nr)
#pragma unroll
        for (int r = 0; r < 4; ++r) {
          int row = bm + wr * 32 + mr * 16 + g * 4 + r;
          int col = bn + wc * 32 + nr * 16 + li;
          if (row >= M) continue;
          float v = acc[mr][nr][r] + bias[col];
          if (EPI == 0) v *= QSC;
          if (EPI == 1) v = gelu_exact(v);
          C[(long)row * ((EPI == 1) ? FF : D) + col] = f2bs(v);
        }
  }
}

// ---------------------------------------------------------------------------
// Fused flash attention (R6-proven structure): 256 threads = 4 split-K waves
// per (b,h,32-q tile). Wave-private LDS double-buffer via global_load_lds DMA
// (no barriers in the loop, counted vmcnt). No-max exp2 softmax (scores O(1),
// softmax shift-invariant, fp32 exp2 cannot overflow here) -> plain-sum
// split-K combine. XCD-aware block swizzle. Q pre-scaled at projection.
// ---------------------------------------------------------------------------
__global__ __launch_bounds__(256) void attn_mfma(
    const u16* __restrict__ Qb, const u16* __restrict__ Kh,
    const u16* __restrict__ Vh, u16* __restrict__ AO) {
  __shared__ alignas(16) char pool[NSPLIT * 8192];  // 32 KB
  int i = blockIdx.x;
  int xcd = i & 7, slot = i >> 3;          // 66 slots per XCD
  int bh = (xcd << 1) | (slot >= NQT ? 1 : 0);
  int qt = (slot >= NQT) ? slot - NQT : slot;
  int h = bh & 7;
  int b = bh >> 3;
  int tid = threadIdx.x, w = tid >> 6, lane = tid & 63;
  int g = lane >> 4, li = lane & 15;

  fr qf0, qf1;  // Q pre-scaled by QSC at projection time
  {
    int qr0 = qt * 32 + li;
    int qr1 = qt * 32 + 16 + li;
    if (qr0 >= Q_MAX) qr0 = Q_MAX - 1;
    if (qr1 >= Q_MAX) qr1 = Q_MAX - 1;
    qf0.h = *reinterpret_cast<const bf16x8*>(
        Qb + ((long)(b * Q_MAX + qr0)) * D + h * HD + g * 8);
    qf1.h = *reinterpret_cast<const bf16x8*>(
        Qb + ((long)(b * Q_MAX + qr1)) * D + h * HD + g * 8);
  }

  f32x4 acc00 = {}, acc01 = {}, acc10 = {}, acc11 = {};
  float den0 = 0.f, den1 = 0.f;
  const f32x4 z = {};

  const u16* kbase = Kh + ((long)(b * H + h) * L) * HD;
  const u16* vbase = Vh + ((long)(b * H + h) * L) * HD;
  int kstart = w * KCHUNK;
  char* wbase = pool + w * 8192;  // wave-private: 2 bufs x (2KB K + 2KB V)

  // prologue: stage tile 0 into buf 0
  {
    const u16* ks = kbase + (long)kstart * HD + lane * 8;
    const u16* vs = vbase + (long)kstart * HD + lane * 8;
    u16* lk = (u16*)wbase;
    GLL16(ks, lk);
    GLL16(ks + 512, lk + 512);
    GLL16(vs, lk + 1024);
    GLL16(vs + 512, lk + 1536);
  }

  for (int t = 0; t < NT; ++t) {
    char* cbuf = wbase + (t & 1) * 4096;
    if (t + 1 < NT) {
      char* nbuf = wbase + ((t + 1) & 1) * 4096;
      const u16* ks = kbase + (long)(kstart + (t + 1) * 32) * HD + lane * 8;
      const u16* vs = vbase + (long)(kstart + (t + 1) * 32) * HD + lane * 8;
      u16* lk = (u16*)nbuf;
      GLL16(ks, lk);
      GLL16(ks + 512, lk + 512);
      GLL16(vs, lk + 1024);
      GLL16(vs + 512, lk + 1536);
      asm volatile("s_waitcnt vmcnt(4)" ::: "memory");
    } else {
      asm volatile("s_waitcnt vmcnt(0)" ::: "memory");
    }
    __builtin_amdgcn_sched_barrier(0);

    const u16* kl = (const u16*)cbuf;
    const u16* vl = kl + 1024;
    bf16x8 kf0 = *reinterpret_cast<const bf16x8*>(kl + li * 32 + g * 8);
    bf16x8 kf1 = *reinterpret_cast<const bf16x8*>(kl + (16 + li) * 32 + g * 8);
    uint2 va0 = *reinterpret_cast<const uint2*>(vl + li * 32 + 4 * g);
    uint2 vb0 = *reinterpret_cast<const uint2*>(vl + li * 32 + 16 + 4 * g);
    uint2 va1 = *reinterpret_cast<const uint2*>(vl + (16 + li) * 32 + 4 * g);
    uint2 vb1 = *reinterpret_cast<const uint2*>(vl + (16 + li) * 32 + 16 + 4 * g);

    f32x4 s00 = __builtin_amdgcn_mfma_f32_16x16x32_bf16(kf0, qf0.h, z, 0, 0, 0);
    f32x4 s10 = __builtin_amdgcn_mfma_f32_16x16x32_bf16(kf1, qf0.h, z, 0, 0, 0);
    f32x4 s01 = __builtin_amdgcn_mfma_f32_16x16x32_bf16(kf0, qf1.h, z, 0, 0, 0);
    f32x4 s11 = __builtin_amdgcn_mfma_f32_16x16x32_bf16(kf1, qf1.h, z, 0, 0, 0);

    float p00[4], p10[4], p01[4], p11[4];
#pragma unroll
    for (int r = 0; r < 4; ++r) {
      p00[r] = exp2f(s00[r]);
      p10[r] = exp2f(s10[r]);
      p01[r] = exp2f(s01[r]);
      p11[r] = exp2f(s11[r]);
      den0 += p00[r] + p10[r];
      den1 += p01[r] + p11[r];
    }
    fr pf0, pf1;
    pf0.i[0] = (int)cvt_pk(p00[0], p00[1]);
    pf0.i[1] = (int)cvt_pk(p00[2], p00[3]);
    pf0.i[2] = (int)cvt_pk(p10[0], p10[1]);
    pf0.i[3] = (int)cvt_pk(p10[2], p10[3]);
    pf1.i[0] = (int)cvt_pk(p01[0], p01[1]);
    pf1.i[1] = (int)cvt_pk(p01[2], p01[3]);
    pf1.i[2] = (int)cvt_pk(p11[0], p11[1]);
    pf1.i[3] = (int)cvt_pk(p11[2], p11[3]);

    fr v0, v1;
    v0.i = (i32x4){(int)va0.x, (int)va0.y, (int)vb0.x, (int)vb0.y};
    v1.i = (i32x4){(int)va1.x, (int)va1.y, (int)vb1.x, (int)vb1.y};
    acc00 = __builtin_amdgcn_mfma_f32_16x16x32_bf16(v0.h, pf0.h, acc00, 0, 0, 0);
    acc01 = __builtin_amdgcn_mfma_f32_16x16x32_bf16(v0.h, pf1.h, acc01, 0, 0, 0);
    acc10 = __builtin_amdgcn_mfma_f32_16x16x32_bf16(v1.h, pf0.h, acc10, 0, 0, 0);
    acc11 = __builtin_amdgcn_mfma_f32_16x16x32_bf16(v1.h, pf1.h, acc11, 0, 0, 0);
  }

  // reduce per-lane denominators over g
  den0 += __shfl_xor(den0, 16, 64);
  den0 += __shfl_xor(den0, 32, 64);
  den1 += __shfl_xor(den1, 16, 64);
  den1 += __shfl_xor(den1, 32, 64);

  // combine: overlay staging LDS (all waves done with it after barrier)
  __syncthreads();
  float (*accs)[32][33] = (float(*)[32][33])pool;
  float (*dsh)[32] = (float(*)[32])(pool + NSPLIT * 32 * 33 * 4);
#pragma unroll
  for (int r = 0; r < 4; ++r) {
    accs[w][g * 4 + r][li] = acc00[r];
    accs[w][g * 4 + r][16 + li] = acc01[r];
    accs[w][16 + g * 4 + r][li] = acc10[r];
    accs[w][16 + g * 4 + r][16 + li] = acc11[r];
  }
  if (g == 0) {
    dsh[w][li] = den0;
    dsh[w][16 + li] = den1;
  }
  __syncthreads();

  int q = tid >> 3, d4 = (tid & 7) * 4;
  float Den = dsh[0][q] + dsh[1][q] + dsh[2][q] + dsh[3][q];
  float inv = 1.f / Den;
  float o[4];
#pragma unroll
  for (int j = 0; j < 4; ++j)
    o[j] = accs[0][d4 + j][q] + accs[1][d4 + j][q] + accs[2][d4 + j][q] +
           accs[3][d4 + j][q];
  int qrow = qt * 32 + q;
  if (qrow < Q_MAX) {
    uint2 pk = {cvt_pk(o[0] * inv, o[1] * inv), cvt_pk(o[2] * inv, o[3] * inv)};
    *reinterpret_cast<uint2*>(
        AO + ((long)(b * Q_MAX + qrow)) * D + h * HD + d4) = pk;
  }
}

// ---------------------------------------------------------------------------
__global__ __launch_bounds__(256) void head_kernel(
    const float* __restrict__ enc, const float* __restrict__ hW,
    const float* __restrict__ hb, float* __restrict__ out) {
  int row = blockIdx.x * 4 + (threadIdx.x >> 6);
  int lane = threadIdx.x & 63;
  const float4 a = *reinterpret_cast<const float4*>(enc + (long)row * D + lane * 4);
  float c0 = 0.f, c1 = 0.f, c2 = 0.f;
  const float av[4] = {a.x, a.y, a.z, a.w};
#pragma unroll
  for (int i = 0; i < 4; ++i) {
    int k = lane * 4 + i;
    c0 += av[i] * hW[k * 3];
    c1 += av[i] * hW[k * 3 + 1];
    c2 += av[i] * hW[k * 3 + 2];
  }
#pragma unroll
  for (int off = 32; off; off >>= 1) {
    c0 += __shfl_down(c0, off, 64);
    c1 += __shfl_down(c1, off, 64);
    c2 += __shfl_down(c2, off, 64);
  }
  if (lane == 0) {
    out[(long)row * 3] = c0 + hb[0];
    out[(long)row * 3 + 1] = c1 + hb[1];
    out[(long)row * 3 + 2] = c2 + hb[2];
  }
}

// ---------------------------------------------------------------------------
__global__ __launch_bounds__(64) void overwrite_kernel(
    const float* __restrict__ q_stream, const int* __restrict__ idx,
    const int* __restrict__ mask, const float* __restrict__ hW,
    const float* __restrict__ hb, float* __restrict__ out) {
  int j = blockIdx.x;
  if (!mask[j]) return;
  int b = j / Q_MAX;
  int p = idx[j];
  int lane = threadIdx.x;
  const float* a = q_stream + (long)j * D;
  float a0 = a[lane], a1 = a[lane + 64], a2 = a[lane + 128],
        a3 = a[lane + 192];
  for (int c = 0; c < 3; ++c) {
    float s = a0 * hW[lane * 3 + c] + a1 * hW[(lane + 64) * 3 + c] +
              a2 * hW[(lane + 128) * 3 + c] + a3 * hW[(lane + 192) * 3 + c];
    for (int off = 32; off > 0; off >>= 1) s += __shfl_down(s, off, 64);
    if (lane == 0) out[((long)b * L + p) * 3 + c] = s + hb[c];
  }
}

// ---------------------------------------------------------------------------
extern "C" void kernel_launch(void* const* d_in, const int* in_sizes, int n_in,
                              void* d_out, int out_size, void* d_ws,
                              size_t ws_size, hipStream_t stream) {
  const float* enc = (const float*)d_in[0];
  const float* clog = (const float*)d_in[1];
  const float* ln_q_g = (const float*)d_in[2];
  const float* ln_q_b = (const float*)d_in[3];
  const float* ln_kv_g = (const float*)d_in[4];
  const float* ln_kv_b = (const float*)d_in[5];
  const float* Wq = (const float*)d_in[6];
  const float* bq = (const float*)d_in[7];
  const float* Wk = (const float*)d_in[8];
  const float* bk = (const float*)d_in[9];
  const float* Wv = (const float*)d_in[10];
  const float* bv = (const float*)d_in[11];
  const float* Wo = (const float*)d_in[12];
  const float* bo = (const float*)d_in[13];
  const float* ffn_g = (const float*)d_in[14];
  const float* ffn_b = (const float*)d_in[15];
  const float* W1 = (const float*)d_in[16];
  const float* b1 = (const float*)d_in[17];
  const float* W2 = (const float*)d_in[18];
  const float* b2 = (const float*)d_in[19];
  const float* head_W = (const float*)d_in[20];
  const float* head_b = (const float*)d_in[21];
  float* out = (float*)d_out;

  char* ws = (char*)d_ws;
  float* q_stream = (float*)ws;            ws += (long)QROWS * D * 4;
  u16* Khbuf = (u16*)ws;                   ws += (long)B * H * L * HD * 2;
  u16* Vhbuf = (u16*)ws;                   ws += (long)B * H * L * HD * 2;
  u16* Qbuf = (u16*)ws;                    ws += (long)QROWS * D * 2;
  u16* AObuf = (u16*)ws;                   ws += (long)QROWS * D * 2;
  u16* H1buf = (u16*)ws;                   ws += (long)QROWS * FF * 2;
  u16* WT = (u16*)ws;                      ws += (long)NL * (4 * D * D + 2 * D * FF) * 2;
  int* idxbuf = (int*)ws;                  ws += QROWS * 4;
  int* maskbuf = (int*)ws;

  const long DD = (long)D * D, DFF = (long)D * FF;
  const long LSTR = 4 * DD + 2 * DFF;

  transpose_all<<<(int)((NL * LSTR + 255) / 256), 256, 0, stream>>>(
      Wq, Wk, Wv, Wo, W1, W2, WT);
  select_kernel<<<B, 1024, 0, stream>>>(clog, idxbuf, maskbuf);
  gather_kernel<<<QROWS, 256, 0, stream>>>(enc, idxbuf, q_stream);

  for (int l = 0; l < NL; ++l) {
    u16* base = WT + l * LSTR;

    // K+V projection with fused LN(enc) -> Kh/Vh (R6 layouts)
    gemm_ln<2><<<dim3(8, KVROWS / 64), 256, 0, stream>>>(
        enc, base, ln_kv_g + l * D, ln_kv_b + l * D, bk + l * D, bv + l * D,
        Khbuf, Vhbuf, KVROWS);
    // Q projection with fused LN(q_stream), pre-scaled by QSC
    gemm_ln<0><<<dim3(4, (QROWS + 63) / 64), 256, 0, stream>>>(
        q_stream, base + 2 * DD, ln_q_g + l * D, ln_q_b + l * D, bq + l * D,
        nullptr, Qbuf, nullptr, QROWS);

    attn_mfma<<<B * H * NQT, 256, 0, stream>>>(Qbuf, Khbuf, Vhbuf, AObuf);

    dim3 gQ(D / 64, (QROWS + 63) / 64);
    gemm_mfma<2><<<gQ, 256, 0, stream>>>(AObuf, base + 3 * DD, bo + l * D,
                                         (void*)q_stream, q_stream, maskbuf,
                                         QROWS, D, D);

    // FFN-1 with fused LN(q_stream)
    gemm_ln<1><<<dim3(FF / 64, (QROWS + 63) / 64), 256, 0, stream>>>(
        q_stream, base + 4 * DD, ffn_g + l * D, ffn_b + l * D, b1 + l * FF,
        nullptr, H1buf, nullptr, QROWS);
    dim3 gF2(D / 64, (QROWS + 63) / 64);
    gemm_mfma<2><<<gF2, 256, 0, stream>>>(H1buf, base + 4 * DD + DFF,
                                          b2 + l * D, (void*)q_stream,
                                          q_stream, maskbuf, QROWS, D, FF);
  }

  head_kernel<<<KVROWS / 4, 256, 0, stream>>>(enc, head_W, head_b, out);
  overwrite_kernel<<<QROWS, 64, 0, stream>>>(q_stream, idxbuf, maskbuf, head_W,
                                             head_b, out);
}

// Round 9
// 254.726 us; speedup vs baseline: 1.3537x; 1.3537x over previous
//
#include <hip/hip_runtime.h>
#include <cmath>

constexpr int B = 2, L = 4096, D = 256, H = 8, NC = 3;
constexpr int TOP_N = 8, R = 32;
constexpr int LS = 1000, LE = 3000;
constexpr int NL = 2;
constexpr int FF = 4 * D;                        // 1024
constexpr int Q_MAX = 2 * TOP_N * (2 * R + 1);   // 1040
constexpr int HD = D / H;                        // 32
constexpr int QROWS = B * Q_MAX;                 // 2080
constexpr int KVROWS = B * L;                    // 8192
constexpr int NQT = (Q_MAX + 31) / 32;           // 33 q-tiles of 32
constexpr int NREG = LE - LS;                    // 2000
constexpr int NSPLIT = 8;                        // split-K waves per block
constexpr int KCHUNK = L / NSPLIT;               // 512 keys per wave
constexpr int NT = KCHUNK / 32;                  // 16 iterations

typedef __attribute__((ext_vector_type(8))) short bf16x8;
typedef __attribute__((ext_vector_type(4))) float f32x4;
typedef __attribute__((ext_vector_type(4))) int i32x4;
typedef unsigned short u16;

union fr {
  bf16x8 h;
  i32x4 i;
};

__device__ __forceinline__ u16 f2bs(float f) {
  unsigned int u = __float_as_uint(f);
  unsigned int r = u + 0x7fffu + ((u >> 16) & 1u);
  return (u16)(r >> 16);
}
__device__ __forceinline__ float bs2f(u16 s) {
  return __uint_as_float(((unsigned int)s) << 16);
}
__device__ __forceinline__ float gelu_exact(float x) {
  return 0.5f * x * (1.f + erff(x * 0.70710678118654752440f));
}
__device__ __forceinline__ unsigned cvt_pk(float lo, float hi) {
  unsigned r;
  asm("v_cvt_pk_bf16_f32 %0, %1, %2" : "=v"(r) : "v"(lo), "v"(hi));
  return r;
}

#define GLL16(gsrc, ldst)                                                   \
  __builtin_amdgcn_global_load_lds(                                         \
      (const __attribute__((address_space(1))) unsigned int*)(gsrc),        \
      (__attribute__((address_space(3))) unsigned int*)(ldst), 16, 0, 0)

// ---------------------------------------------------------------------------
// Vicinity selection. One 1024-thread block per batch.
// ---------------------------------------------------------------------------
__global__ __launch_bounds__(1024) void select_kernel(
    const float* __restrict__ logits, int* __restrict__ idx_out,
    int* __restrict__ mask_out) {
  int b = blockIdx.x;
  int tid = threadIdx.x;
  __shared__ float vv[2][NREG];
  __shared__ int centers[2 * TOP_N];
  __shared__ unsigned present[L / 32];
  __shared__ float wred[16];
  __shared__ int wredi[16];
  __shared__ int offs[128];
  __shared__ int wtot[2];

  for (int p = tid; p < NREG; p += 1024) {
    const float* lg = logits + ((long)b * L + LS + p) * NC;
    float x0 = lg[0], x1 = lg[1], x2 = lg[2];
    float m = fmaxf(x0, fmaxf(x1, x2));
    float lse = m + logf(expf(x0 - m) + expf(x1 - m) + expf(x2 - m));
    vv[0][p] = x2 - lse;  // don
    vv[1][p] = x1 - lse;  // acc
  }
  if (tid < 128) present[tid] = 0;
  __syncthreads();

  for (int sel = 0; sel < 2; ++sel) {
    for (int t = 0; t < TOP_N; ++t) {
      float bv = -INFINITY;
      int bi = 0x7fffffff;
      for (int p = tid; p < NREG; p += 1024) {
        float x = vv[sel][p];
        if (x > bv || (x == bv && p < bi)) { bv = x; bi = p; }
      }
#pragma unroll
      for (int off = 32; off; off >>= 1) {
        float ov = __shfl_xor(bv, off, 64);
        int oi = __shfl_xor(bi, off, 64);
        if (ov > bv || (ov == bv && oi < bi)) { bv = ov; bi = oi; }
      }
      if ((tid & 63) == 0) { wred[tid >> 6] = bv; wredi[tid >> 6] = bi; }
      __syncthreads();
      if (tid < 64) {
        bv = (tid < 16) ? wred[tid] : -INFINITY;
        bi = (tid < 16) ? wredi[tid] : 0x7fffffff;
#pragma unroll
        for (int off = 8; off; off >>= 1) {
          float ov = __shfl_xor(bv, off, 64);
          int oi = __shfl_xor(bi, off, 64);
          if (ov > bv || (ov == bv && oi < bi)) { bv = ov; bi = oi; }
        }
        if (tid == 0) {
          centers[sel * TOP_N + t] = LS + bi;
          vv[sel][bi] = -INFINITY;
        }
      }
      __syncthreads();
    }
  }

  for (int j = tid; j < Q_MAX; j += 1024) {
    int c = centers[j / (2 * R + 1)];
    int off = j % (2 * R + 1) - R;
    int v = c + off;
    v = v < 0 ? 0 : (v > L - 1 ? L - 1 : v);
    atomicOr(&present[v >> 5], 1u << (v & 31));
  }
  __syncthreads();

  int cnt = (tid < 128) ? __popc(present[tid]) : 0;
  if (tid < 128) {
    int x = cnt;
#pragma unroll
    for (int off = 1; off < 64; off <<= 1) {
      int o = __shfl_up(x, off, 64);
      if ((tid & 63) >= off) x += o;
    }
    if ((tid & 63) == 63) wtot[tid >> 6] = x;
    offs[tid] = x - cnt;
  }
  __syncthreads();
  int total = wtot[0] + wtot[1];
  if (tid < 128) {
    int base = offs[tid] + ((tid >= 64) ? wtot[0] : 0);
    unsigned mword = present[tid];
    while (mword) {
      int i = __ffs(mword) - 1;
      mword &= mword - 1;
      idx_out[b * Q_MAX + base] = tid * 32 + i;
      mask_out[b * Q_MAX + base] = 1;
      ++base;
    }
  }
  for (int j = total + tid; j < Q_MAX; j += 1024) {
    idx_out[b * Q_MAX + j] = L;
    mask_out[b * Q_MAX + j] = 0;
  }
}

// ---------------------------------------------------------------------------
__global__ __launch_bounds__(256) void gather_kernel(
    const float* __restrict__ enc, const int* __restrict__ idx,
    float* __restrict__ q_stream) {
  int row = blockIdx.x;
  int b = row / Q_MAX;
  int p = idx[row];
  float v = 0.f;
  if (p < L) v = enc[((long)b * L + p) * D + threadIdx.x];
  q_stream[(long)row * D + threadIdx.x] = v;
}

// ---------------------------------------------------------------------------
__global__ __launch_bounds__(256) void ln_bf16(
    const float* __restrict__ in, u16* __restrict__ out,
    const float* __restrict__ gg, const float* __restrict__ bb) {
  long row = blockIdx.x;
  int tid = threadIdx.x;
  float x = in[row * D + tid];
  float s1 = x, s2 = x * x;
#pragma unroll
  for (int off = 32; off; off >>= 1) {
    s1 += __shfl_xor(s1, off, 64);
    s2 += __shfl_xor(s2, off, 64);
  }
  __shared__ float p1[4], p2[4];
  int w = tid >> 6;
  if ((tid & 63) == 0) { p1[w] = s1; p2[w] = s2; }
  __syncthreads();
  s1 = p1[0] + p1[1] + p1[2] + p1[3];
  s2 = p2[0] + p2[1] + p2[2] + p2[3];
  float mean = s1 * (1.f / D);
  float var = fmaxf(s2 * (1.f / D) - mean * mean, 0.f);
  float r = rsqrtf(var + 1e-5f);
  out[row * D + tid] = f2bs((x - mean) * r * gg[tid] + bb[tid]);
}

__global__ __launch_bounds__(256) void ln_kv2(
    const float* __restrict__ in, u16* __restrict__ o0, u16* __restrict__ o1,
    const float* __restrict__ g) {
  long row = blockIdx.x;
  int tid = threadIdx.x;
  float x = in[row * D + tid];
  float s1 = x, s2 = x * x;
#pragma unroll
  for (int off = 32; off; off >>= 1) {
    s1 += __shfl_xor(s1, off, 64);
    s2 += __shfl_xor(s2, off, 64);
  }
  __shared__ float p1[4], p2[4];
  int w = tid >> 6;
  if ((tid & 63) == 0) { p1[w] = s1; p2[w] = s2; }
  __syncthreads();
  s1 = p1[0] + p1[1] + p1[2] + p1[3];
  s2 = p2[0] + p2[1] + p2[2] + p2[3];
  float mean = s1 * (1.f / D);
  float var = fmaxf(s2 * (1.f / D) - mean * mean, 0.f);
  float r = rsqrtf(var + 1e-5f);
  float xn = (x - mean) * r;
  o0[row * D + tid] = f2bs(xn * g[tid] + g[2 * D + tid]);
  o1[row * D + tid] = f2bs(xn * g[D + tid] + g[3 * D + tid]);
}

__global__ __launch_bounds__(256) void pack_lnkv(
    const float* __restrict__ g, const float* __restrict__ bb,
    float* __restrict__ dst) {
  int t = blockIdx.x * 256 + threadIdx.x;
  if (t < 2 * D) dst[t] = g[t];
  else if (t < 4 * D) dst[t] = bb[t - 2 * D];
}

// ---------------------------------------------------------------------------
__global__ __launch_bounds__(256) void transpose_all(
    const float* __restrict__ Wq_, const float* __restrict__ Wk_,
    const float* __restrict__ Wv_, const float* __restrict__ Wo_,
    const float* __restrict__ W1_, const float* __restrict__ W2_,
    u16* __restrict__ WT) {
  const long DD = (long)D * D, DFF = (long)D * FF;
  const long LSTR = 4 * DD + 2 * DFF;
  long t = (long)blockIdx.x * 256 + threadIdx.x;
  if (t >= NL * LSTR) return;
  int l = (int)(t / LSTR);
  long r = t - (long)l * LSTR;
  const float* src;
  long dstbase, e;
  int K_, N_;
  if (r < 4 * DD) {
    int which = (int)(r >> 16);
    e = r & (DD - 1);
    K_ = D; N_ = D;
    src = (which == 0 ? Wk_ : which == 1 ? Wv_ : which == 2 ? Wq_ : Wo_) +
          (long)l * DD;
    dstbase = l * LSTR + which * DD;
  } else if (r < 4 * DD + DFF) {
    e = r - 4 * DD;
    K_ = D; N_ = FF;
    src = W1_ + (long)l * DFF;
    dstbase = l * LSTR + 4 * DD;
  } else {
    e = r - 4 * DD - DFF;
    K_ = FF; N_ = D;
    src = W2_ + (long)l * DFF;
    dstbase = l * LSTR + 4 * DD + DFF;
  }
  int k = (int)(e / N_), n = (int)(e % N_);
  WT[dstbase + (long)n * K_ + k] = f2bs(src[e]);
}

// ---------------------------------------------------------------------------
// bf16 MFMA GEMM (64x64 tile, BK=32, 4 waves).
// EPI 0: bias->bf16; 1: gelu->bf16; 2: resid+mask->f32
// ---------------------------------------------------------------------------
template <int EPI>
__global__ __launch_bounds__(256) void gemm_mfma(
    const u16* __restrict__ A, const u16* __restrict__ BT,
    const float* __restrict__ bias, void* __restrict__ Cv,
    const float* __restrict__ resid, const int* __restrict__ mask, int M,
    int N, int K) {
  __shared__ short As[64][40];
  __shared__ short Bs[64][40];
  int bm = blockIdx.y * 64, bn = blockIdx.x * 64;
  int tid = threadIdx.x;
  int lane = tid & 63, w = tid >> 6;
  int g = lane >> 4, li = lane & 15;
  int wr = w >> 1, wc = w & 1;
  f32x4 acc[2][2] = {};

  int srow = tid >> 2, skc = (tid & 3) * 8;
  for (int k0 = 0; k0 < K; k0 += 32) {
    {
      int grow = bm + srow;
      bf16x8 av = {};
      if (grow < M)
        av = *reinterpret_cast<const bf16x8*>(A + (long)grow * K + k0 + skc);
      *reinterpret_cast<bf16x8*>(&As[srow][skc]) = av;
      bf16x8 bv = *reinterpret_cast<const bf16x8*>(
          BT + (long)(bn + srow) * K + k0 + skc);
      *reinterpret_cast<bf16x8*>(&Bs[srow][skc]) = bv;
    }
    __syncthreads();
    bf16x8 a0 = *reinterpret_cast<const bf16x8*>(&As[wr * 32 + li][g * 8]);
    bf16x8 a1 = *reinterpret_cast<const bf16x8*>(&As[wr * 32 + 16 + li][g * 8]);
    bf16x8 b0 = *reinterpret_cast<const bf16x8*>(&Bs[wc * 32 + li][g * 8]);
    bf16x8 b1 = *reinterpret_cast<const bf16x8*>(&Bs[wc * 32 + 16 + li][g * 8]);
    acc[0][0] = __builtin_amdgcn_mfma_f32_16x16x32_bf16(a0, b0, acc[0][0], 0, 0, 0);
    acc[0][1] = __builtin_amdgcn_mfma_f32_16x16x32_bf16(a0, b1, acc[0][1], 0, 0, 0);
    acc[1][0] = __builtin_amdgcn_mfma_f32_16x16x32_bf16(a1, b0, acc[1][0], 0, 0, 0);
    acc[1][1] = __builtin_amdgcn_mfma_f32_16x16x32_bf16(a1, b1, acc[1][1], 0, 0, 0);
    __syncthreads();
  }

#pragma unroll
  for (int mr = 0; mr < 2; ++mr)
#pragma unroll
    for (int nr = 0; nr < 2; ++nr)
#pragma unroll
      for (int r = 0; r < 4; ++r) {
        int row = bm + wr * 32 + mr * 16 + g * 4 + r;
        int col = bn + wc * 32 + nr * 16 + li;
        if (row >= M) continue;
        float v = acc[mr][nr][r] + bias[col];
        if (EPI == 1) v = gelu_exact(v);
        if (EPI == 2) {
          v += resid[(long)row * N + col];
          v = mask[row] ? v : 0.f;
          ((float*)Cv)[(long)row * N + col] = v;
        } else {
          ((u16*)Cv)[(long)row * N + col] = f2bs(v);
        }
      }
}

// ---------------------------------------------------------------------------
// Fused K+V projection GEMM: A = kv_ln [8192x256], BT = [WkT; WvT] (512x256).
// bn < 256 -> Kh[b][h][key][d]; bn >= 256 -> Vh[b][h][key/32][d][key%32].
// ---------------------------------------------------------------------------
__global__ __launch_bounds__(256) void gemm_kv(
    const u16* __restrict__ A, const u16* __restrict__ BT,
    const float* __restrict__ biasK, const float* __restrict__ biasV,
    u16* __restrict__ Kh, u16* __restrict__ Vh) {
  __shared__ short As[64][40];
  __shared__ short Bs[64][40];
  int bm = blockIdx.y * 64, bn = blockIdx.x * 64;
  int tid = threadIdx.x;
  int lane = tid & 63, w = tid >> 6;
  int g = lane >> 4, li = lane & 15;
  int wr = w >> 1, wc = w & 1;
  f32x4 acc[2][2] = {};

  int srow = tid >> 2, skc = (tid & 3) * 8;
  for (int k0 = 0; k0 < D; k0 += 32) {
    {
      bf16x8 av = *reinterpret_cast<const bf16x8*>(
          A + (long)(bm + srow) * D + k0 + skc);
      *reinterpret_cast<bf16x8*>(&As[srow][skc]) = av;
      bf16x8 bv = *reinterpret_cast<const bf16x8*>(
          BT + (long)(bn + srow) * D + k0 + skc);
      *reinterpret_cast<bf16x8*>(&Bs[srow][skc]) = bv;
    }
    __syncthreads();
    bf16x8 a0 = *reinterpret_cast<const bf16x8*>(&As[wr * 32 + li][g * 8]);
    bf16x8 a1 = *reinterpret_cast<const bf16x8*>(&As[wr * 32 + 16 + li][g * 8]);
    bf16x8 b0 = *reinterpret_cast<const bf16x8*>(&Bs[wc * 32 + li][g * 8]);
    bf16x8 b1 = *reinterpret_cast<const bf16x8*>(&Bs[wc * 32 + 16 + li][g * 8]);
    acc[0][0] = __builtin_amdgcn_mfma_f32_16x16x32_bf16(a0, b0, acc[0][0], 0, 0, 0);
    acc[0][1] = __builtin_amdgcn_mfma_f32_16x16x32_bf16(a0, b1, acc[0][1], 0, 0, 0);
    acc[1][0] = __builtin_amdgcn_mfma_f32_16x16x32_bf16(a1, b0, acc[1][0], 0, 0, 0);
    acc[1][1] = __builtin_amdgcn_mfma_f32_16x16x32_bf16(a1, b1, acc[1][1], 0, 0, 0);
    __syncthreads();
  }

  if (bn < 256) {
    __shared__ u16 Ct[64][72];
#pragma unroll
    for (int mr = 0; mr < 2; ++mr)
#pragma unroll
      for (int nr = 0; nr < 2; ++nr)
#pragma unroll
        for (int r = 0; r < 4; ++r) {
          int rowL = wr * 32 + mr * 16 + g * 4 + r;
          int colL = wc * 32 + nr * 16 + li;
          Ct[rowL][colL] = f2bs(acc[mr][nr][r] + biasK[bn + colL]);
        }
    __syncthreads();
#pragma unroll
    for (int p = 0; p < 2; ++p) {
      int rowL = (tid >> 3) + p * 32;
      int c8 = (tid & 7) * 8;
      int grow = bm + rowL;
      int b2 = grow >> 12, key = grow & (L - 1);
      int gcol = bn + c8;
      int hh = gcol >> 5, dd = gcol & (HD - 1);
      u16* dst = Kh + (((long)(b2 * H + hh) * L + key) * 32 + dd);
      *reinterpret_cast<bf16x8*>(dst) =
          *reinterpret_cast<const bf16x8*>(&Ct[rowL][c8]);
    }
  } else {
    int vbn = bn - 256;
    __shared__ u16 Ct[64][72];
#pragma unroll
    for (int mr = 0; mr < 2; ++mr)
#pragma unroll
      for (int nr = 0; nr < 2; ++nr)
#pragma unroll
        for (int r = 0; r < 4; ++r) {
          int rowL = wr * 32 + mr * 16 + g * 4 + r;
          int colL = wc * 32 + nr * 16 + li;
          Ct[colL][rowL] = f2bs(acc[mr][nr][r] + biasV[vbn + colL]);
        }
    __syncthreads();
    int b2 = bm >> 12;
#pragma unroll
    for (int p = 0; p < 2; ++p) {
      int colL = (tid >> 3) + p * 32;
      int rem = tid & 7;
      int kb = rem >> 2, k8 = (rem & 3) * 8;
      int gcol = vbn + colL;
      int hh = gcol >> 5, dd = gcol & (HD - 1);
      int kb32 = ((bm & (L - 1)) >> 5) + kb;
      u16* dst = Vh +
                 (((long)(b2 * H + hh) * (L / 32) + kb32) * 1024 + dd * 32 + k8);
      *reinterpret_cast<bf16x8*>(dst) =
          *reinterpret_cast<const bf16x8*>(&Ct[colL][kb * 32 + k8]);
    }
  }
}

// ---------------------------------------------------------------------------
// Fused flash attention: 512 threads = 8 split-K waves per (b,h,32-q tile).
// Wave-private LDS double-buffer via global_load_lds DMA (no barriers in the
// loop, counted vmcnt). No-max exp2 softmax -> plain-sum split-K combine.
// XCD-aware block swizzle. 64KB LDS -> 2 blocks/CU = 16 waves/CU.
// ---------------------------------------------------------------------------
__global__ __launch_bounds__(512) void attn_mfma(
    const u16* __restrict__ Qb, const u16* __restrict__ Kh,
    const u16* __restrict__ Vh, u16* __restrict__ AO) {
  __shared__ alignas(16) char pool[NSPLIT * 8192];  // 64 KB
  int i = blockIdx.x;
  int xcd = i & 7, slot = i >> 3;          // 66 slots per XCD
  int bh = (xcd << 1) | (slot >= NQT ? 1 : 0);
  int qt = (slot >= NQT) ? slot - NQT : slot;
  int h = bh & 7;
  int b = bh >> 3;
  int tid = threadIdx.x, w = tid >> 6, lane = tid & 63;
  int g = lane >> 4, li = lane & 15;

  fr qf0, qf1;
  {
    const float QSC = 0.25509836048f;  // (1/sqrt(32)) * log2(e)
#pragma unroll
    for (int qb = 0; qb < 2; ++qb) {
      int qrow = qt * 32 + qb * 16 + li;
      if (qrow >= Q_MAX) qrow = Q_MAX - 1;
      bf16x8 raw = *reinterpret_cast<const bf16x8*>(
          Qb + ((long)(b * Q_MAX + qrow)) * D + h * HD + g * 8);
      fr& qf = qb ? qf1 : qf0;
#pragma unroll
      for (int j = 0; j < 4; ++j)
        qf.i[j] = (int)cvt_pk(bs2f((u16)raw[2 * j]) * QSC,
                              bs2f((u16)raw[2 * j + 1]) * QSC);
    }
  }

  f32x4 acc00 = {}, acc01 = {}, acc10 = {}, acc11 = {};
  float den0 = 0.f, den1 = 0.f;
  const f32x4 z = {};

  const u16* kbase = Kh + ((long)(b * H + h) * L) * HD;
  const u16* vbase = Vh + ((long)(b * H + h) * L) * HD;
  int kstart = w * KCHUNK;
  char* wbase = pool + w * 8192;  // wave-private: 2 bufs x (2KB K + 2KB V)

  // prologue: stage tile 0 into buf 0
  {
    const u16* ks = kbase + (long)kstart * HD + lane * 8;
    const u16* vs = vbase + (long)kstart * HD + lane * 8;
    u16* lk = (u16*)wbase;
    GLL16(ks, lk);
    GLL16(ks + 512, lk + 512);
    GLL16(vs, lk + 1024);
    GLL16(vs + 512, lk + 1536);
  }

  for (int t = 0; t < NT; ++t) {
    char* cbuf = wbase + (t & 1) * 4096;
    if (t + 1 < NT) {
      char* nbuf = wbase + ((t + 1) & 1) * 4096;
      const u16* ks = kbase + (long)(kstart + (t + 1) * 32) * HD + lane * 8;
      const u16* vs = vbase + (long)(kstart + (t + 1) * 32) * HD + lane * 8;
      u16* lk = (u16*)nbuf;
      GLL16(ks, lk);
      GLL16(ks + 512, lk + 512);
      GLL16(vs, lk + 1024);
      GLL16(vs + 512, lk + 1536);
      asm volatile("s_waitcnt vmcnt(4)" ::: "memory");
    } else {
      asm volatile("s_waitcnt vmcnt(0)" ::: "memory");
    }
    __builtin_amdgcn_sched_barrier(0);

    const u16* kl = (const u16*)cbuf;
    const u16* vl = kl + 1024;
    bf16x8 kf0 = *reinterpret_cast<const bf16x8*>(kl + li * 32 + g * 8);
    bf16x8 kf1 = *reinterpret_cast<const bf16x8*>(kl + (16 + li) * 32 + g * 8);
    uint2 va0 = *reinterpret_cast<const uint2*>(vl + li * 32 + 4 * g);
    uint2 vb0 = *reinterpret_cast<const uint2*>(vl + li * 32 + 16 + 4 * g);
    uint2 va1 = *reinterpret_cast<const uint2*>(vl + (16 + li) * 32 + 4 * g);
    uint2 vb1 = *reinterpret_cast<const uint2*>(vl + (16 + li) * 32 + 16 + 4 * g);

    f32x4 s00 = __builtin_amdgcn_mfma_f32_16x16x32_bf16(kf0, qf0.h, z, 0, 0, 0);
    f32x4 s10 = __builtin_amdgcn_mfma_f32_16x16x32_bf16(kf1, qf0.h, z, 0, 0, 0);
    f32x4 s01 = __builtin_amdgcn_mfma_f32_16x16x32_bf16(kf0, qf1.h, z, 0, 0, 0);
    f32x4 s11 = __builtin_amdgcn_mfma_f32_16x16x32_bf16(kf1, qf1.h, z, 0, 0, 0);

    float p00[4], p10[4], p01[4], p11[4];
#pragma unroll
    for (int r = 0; r < 4; ++r) {
      p00[r] = exp2f(s00[r]);
      p10[r] = exp2f(s10[r]);
      p01[r] = exp2f(s01[r]);
      p11[r] = exp2f(s11[r]);
      den0 += p00[r] + p10[r];
      den1 += p01[r] + p11[r];
    }
    fr pf0, pf1;
    pf0.i[0] = (int)cvt_pk(p00[0], p00[1]);
    pf0.i[1] = (int)cvt_pk(p00[2], p00[3]);
    pf0.i[2] = (int)cvt_pk(p10[0], p10[1]);
    pf0.i[3] = (int)cvt_pk(p10[2], p10[3]);
    pf1.i[0] = (int)cvt_pk(p01[0], p01[1]);
    pf1.i[1] = (int)cvt_pk(p01[2], p01[3]);
    pf1.i[2] = (int)cvt_pk(p11[0], p11[1]);
    pf1.i[3] = (int)cvt_pk(p11[2], p11[3]);

    fr v0, v1;
    v0.i = (i32x4){(int)va0.x, (int)va0.y, (int)vb0.x, (int)vb0.y};
    v1.i = (i32x4){(int)va1.x, (int)va1.y, (int)vb1.x, (int)vb1.y};
    acc00 = __builtin_amdgcn_mfma_f32_16x16x32_bf16(v0.h, pf0.h, acc00, 0, 0, 0);
    acc01 = __builtin_amdgcn_mfma_f32_16x16x32_bf16(v0.h, pf1.h, acc01, 0, 0, 0);
    acc10 = __builtin_amdgcn_mfma_f32_16x16x32_bf16(v1.h, pf0.h, acc10, 0, 0, 0);
    acc11 = __builtin_amdgcn_mfma_f32_16x16x32_bf16(v1.h, pf1.h, acc11, 0, 0, 0);
  }

  // reduce per-lane denominators over g
  den0 += __shfl_xor(den0, 16, 64);
  den0 += __shfl_xor(den0, 32, 64);
  den1 += __shfl_xor(den1, 16, 64);
  den1 += __shfl_xor(den1, 32, 64);

  // combine: overlay staging LDS (all waves done with it after barrier)
  __syncthreads();
  float (*accs)[32][33] = (float(*)[32][33])pool;
  float (*dsh)[32] = (float(*)[32])(pool + NSPLIT * 32 * 33 * 4);
#pragma unroll
  for (int r = 0; r < 4; ++r) {
    accs[w][g * 4 + r][li] = acc00[r];
    accs[w][g * 4 + r][16 + li] = acc01[r];
    accs[w][16 + g * 4 + r][li] = acc10[r];
    accs[w][16 + g * 4 + r][16 + li] = acc11[r];
  }
  if (g == 0) {
    dsh[w][li] = den0;
    dsh[w][16 + li] = den1;
  }
  __syncthreads();

  int q = tid >> 4, dp = tid & 15;  // q 0..31, d-pair 0..15
  float Den = 0.f, o0 = 0.f, o1 = 0.f;
#pragma unroll
  for (int ww = 0; ww < NSPLIT; ++ww) {
    Den += dsh[ww][q];
    o0 += accs[ww][2 * dp][q];
    o1 += accs[ww][2 * dp + 1][q];
  }
  float inv = 1.f / Den;
  int qrow = qt * 32 + q;
  if (qrow < Q_MAX) {
    unsigned pk = cvt_pk(o0 * inv, o1 * inv);
    *reinterpret_cast<unsigned*>(
        AO + ((long)(b * Q_MAX + qrow)) * D + h * HD + 2 * dp) = pk;
  }
}

// ---------------------------------------------------------------------------
__global__ __launch_bounds__(256) void head_kernel(
    const float* __restrict__ enc, const float* __restrict__ hW,
    const float* __restrict__ hb, float* __restrict__ out) {
  int row = blockIdx.x * 4 + (threadIdx.x >> 6);
  int lane = threadIdx.x & 63;
  const float4 a = *reinterpret_cast<const float4*>(enc + (long)row * D + lane * 4);
  float c0 = 0.f, c1 = 0.f, c2 = 0.f;
  const float av[4] = {a.x, a.y, a.z, a.w};
#pragma unroll
  for (int i = 0; i < 4; ++i) {
    int k = lane * 4 + i;
    c0 += av[i] * hW[k * 3];
    c1 += av[i] * hW[k * 3 + 1];
    c2 += av[i] * hW[k * 3 + 2];
  }
#pragma unroll
  for (int off = 32; off; off >>= 1) {
    c0 += __shfl_down(c0, off, 64);
    c1 += __shfl_down(c1, off, 64);
    c2 += __shfl_down(c2, off, 64);
  }
  if (lane == 0) {
    out[(long)row * 3] = c0 + hb[0];
    out[(long)row * 3 + 1] = c1 + hb[1];
    out[(long)row * 3 + 2] = c2 + hb[2];
  }
}

// ---------------------------------------------------------------------------
__global__ __launch_bounds__(64) void overwrite_kernel(
    const float* __restrict__ q_stream, const int* __restrict__ idx,
    const int* __restrict__ mask, const float* __restrict__ hW,
    const float* __restrict__ hb, float* __restrict__ out) {
  int j = blockIdx.x;
  if (!mask[j]) return;
  int b = j / Q_MAX;
  int p = idx[j];
  int lane = threadIdx.x;
  const float* a = q_stream + (long)j * D;
  float a0 = a[lane], a1 = a[lane + 64], a2 = a[lane + 128],
        a3 = a[lane + 192];
  for (int c = 0; c < 3; ++c) {
    float s = a0 * hW[lane * 3 + c] + a1 * hW[(lane + 64) * 3 + c] +
              a2 * hW[(lane + 128) * 3 + c] + a3 * hW[(lane + 192) * 3 + c];
    for (int off = 32; off > 0; off >>= 1) s += __shfl_down(s, off, 64);
    if (lane == 0) out[((long)b * L + p) * 3 + c] = s + hb[c];
  }
}

// ---------------------------------------------------------------------------
extern "C" void kernel_launch(void* const* d_in, const int* in_sizes, int n_in,
                              void* d_out, int out_size, void* d_ws,
                              size_t ws_size, hipStream_t stream) {
  const float* enc = (const float*)d_in[0];
  const float* clog = (const float*)d_in[1];
  const float* ln_q_g = (const float*)d_in[2];
  const float* ln_q_b = (const float*)d_in[3];
  const float* ln_kv_g = (const float*)d_in[4];
  const float* ln_kv_b = (const float*)d_in[5];
  const float* Wq = (const float*)d_in[6];
  const float* bq = (const float*)d_in[7];
  const float* Wk = (const float*)d_in[8];
  const float* bk = (const float*)d_in[9];
  const float* Wv = (const float*)d_in[10];
  const float* bv = (const float*)d_in[11];
  const float* Wo = (const float*)d_in[12];
  const float* bo = (const float*)d_in[13];
  const float* ffn_g = (const float*)d_in[14];
  const float* ffn_b = (const float*)d_in[15];
  const float* W1 = (const float*)d_in[16];
  const float* b1 = (const float*)d_in[17];
  const float* W2 = (const float*)d_in[18];
  const float* b2 = (const float*)d_in[19];
  const float* head_W = (const float*)d_in[20];
  const float* head_b = (const float*)d_in[21];
  float* out = (float*)d_out;

  char* ws = (char*)d_ws;
  float* q_stream = (float*)ws;            ws += (long)QROWS * D * 4;
  u16* kvl0 = (u16*)ws;                    ws += (long)KVROWS * D * 2;
  u16* kvl1 = (u16*)ws;                    ws += (long)KVROWS * D * 2;
  u16* Khbuf = (u16*)ws;                   ws += (long)B * H * L * HD * 2;
  u16* Vhbuf = (u16*)ws;                   ws += (long)B * H * L * HD * 2;
  u16* q_ln = (u16*)ws;                    ws += (long)QROWS * D * 2;
  u16* Qbuf = (u16*)ws;                    ws += (long)QROWS * D * 2;
  u16* AObuf = (u16*)ws;                   ws += (long)QROWS * D * 2;
  u16* H1buf = (u16*)ws;                   ws += (long)QROWS * FF * 2;
  u16* WT = (u16*)ws;                      ws += (long)NL * (4 * D * D + 2 * D * FF) * 2;
  float* lnkv_pack = (float*)ws;           ws += 4 * D * 4;
  int* idxbuf = (int*)ws;                  ws += QROWS * 4;
  int* maskbuf = (int*)ws;

  const long DD = (long)D * D, DFF = (long)D * FF;
  const long LSTR = 4 * DD + 2 * DFF;

  transpose_all<<<(int)((NL * LSTR + 255) / 256), 256, 0, stream>>>(
      Wq, Wk, Wv, Wo, W1, W2, WT);
  pack_lnkv<<<(4 * D + 255) / 256, 256, 0, stream>>>(ln_kv_g, ln_kv_b, lnkv_pack);
  ln_kv2<<<KVROWS, 256, 0, stream>>>(enc, kvl0, kvl1, lnkv_pack);
  select_kernel<<<B, 1024, 0, stream>>>(clog, idxbuf, maskbuf);
  gather_kernel<<<QROWS, 256, 0, stream>>>(enc, idxbuf, q_stream);

  for (int l = 0; l < NL; ++l) {
    u16* base = WT + l * LSTR;
    u16* kv_ln = (l == 0) ? kvl0 : kvl1;

    ln_bf16<<<QROWS, 256, 0, stream>>>(q_stream, q_ln, ln_q_g + l * D, ln_q_b + l * D);

    dim3 gKV(512 / 64, KVROWS / 64);
    gemm_kv<<<gKV, 256, 0, stream>>>(kv_ln, base, bk + l * D, bv + l * D,
                                     Khbuf, Vhbuf);
    dim3 gQ(D / 64, (QROWS + 63) / 64);
    gemm_mfma<0><<<gQ, 256, 0, stream>>>(q_ln, base + 2 * DD, bq + l * D,
                                         (void*)Qbuf, nullptr, nullptr,
                                         QROWS, D, D);

    attn_mfma<<<B * H * NQT, 512, 0, stream>>>(Qbuf, Khbuf, Vhbuf, AObuf);

    gemm_mfma<2><<<gQ, 256, 0, stream>>>(AObuf, base + 3 * DD, bo + l * D,
                                         (void*)q_stream, q_stream, maskbuf,
                                         QROWS, D, D);

    ln_bf16<<<QROWS, 256, 0, stream>>>(q_stream, q_ln, ffn_g + l * D, ffn_b + l * D);
    dim3 gF1(FF / 64, (QROWS + 63) / 64);
    gemm_mfma<1><<<gF1, 256, 0, stream>>>(q_ln, base + 4 * DD, b1 + l * FF,
                                          (void*)H1buf, nullptr, nullptr,
                                          QROWS, FF, D);
    dim3 gF2(D / 64, (QROWS + 63) / 64);
    gemm_mfma<2><<<gF2, 256, 0, stream>>>(H1buf, base + 4 * DD + DFF,
                                          b2 + l * D, (void*)q_stream,
                                          q_stream, maskbuf, QROWS, D, FF);
  }

  head_kernel<<<KVROWS / 4, 256, 0, stream>>>(enc, head_W, head_b, out);
  overwrite_kernel<<<QROWS, 64, 0, stream>>>(q_stream, idxbuf, maskbuf, head_W,
                                             head_b, out);
}

// Round 10
// 252.179 us; speedup vs baseline: 1.3673x; 1.0101x over previous
//
#include <hip/hip_runtime.h>
#include <cmath>

constexpr int B = 2, L = 4096, D = 256, H = 8, NC = 3;
constexpr int TOP_N = 8, R = 32;
constexpr int LS = 1000, LE = 3000;
constexpr int NL = 2;
constexpr int FF = 4 * D;                        // 1024
constexpr int Q_MAX = 2 * TOP_N * (2 * R + 1);   // 1040
constexpr int HD = D / H;                        // 32
constexpr int QROWS = B * Q_MAX;                 // 2080
constexpr int KVROWS = B * L;                    // 8192
constexpr int NQT = (Q_MAX + 31) / 32;           // 33 q-tiles of 32
constexpr int NREG = LE - LS;                    // 2000
constexpr int NSPLIT = 8;                        // split-K waves per block
constexpr int KCHUNK = L / NSPLIT;               // 512 keys per wave
constexpr int NT = KCHUNK / 32;                  // 16 iterations

typedef __attribute__((ext_vector_type(8))) short bf16x8;
typedef __attribute__((ext_vector_type(4))) float f32x4;
typedef __attribute__((ext_vector_type(4))) int i32x4;
typedef unsigned short u16;

union fr {
  bf16x8 h;
  i32x4 i;
};

__device__ __forceinline__ u16 f2bs(float f) {
  unsigned int u = __float_as_uint(f);
  unsigned int r = u + 0x7fffu + ((u >> 16) & 1u);
  return (u16)(r >> 16);
}
__device__ __forceinline__ float bs2f(u16 s) {
  return __uint_as_float(((unsigned int)s) << 16);
}
__device__ __forceinline__ float gelu_exact(float x) {
  return 0.5f * x * (1.f + erff(x * 0.70710678118654752440f));
}
__device__ __forceinline__ unsigned cvt_pk(float lo, float hi) {
  unsigned r;
  asm("v_cvt_pk_bf16_f32 %0, %1, %2" : "=v"(r) : "v"(lo), "v"(hi));
  return r;
}

#define GLL16(gsrc, ldst)                                                   \
  __builtin_amdgcn_global_load_lds(                                         \
      (const __attribute__((address_space(1))) unsigned int*)(gsrc),        \
      (__attribute__((address_space(3))) unsigned int*)(ldst), 16, 0, 0)

// ---------------------------------------------------------------------------
// Vicinity selection. One 1024-thread block per batch.
// ---------------------------------------------------------------------------
__global__ __launch_bounds__(1024) void select_kernel(
    const float* __restrict__ logits, int* __restrict__ idx_out,
    int* __restrict__ mask_out) {
  int b = blockIdx.x;
  int tid = threadIdx.x;
  __shared__ float vv[2][NREG];
  __shared__ int centers[2 * TOP_N];
  __shared__ unsigned present[L / 32];
  __shared__ float wred[16];
  __shared__ int wredi[16];
  __shared__ int offs[128];
  __shared__ int wtot[2];

  for (int p = tid; p < NREG; p += 1024) {
    const float* lg = logits + ((long)b * L + LS + p) * NC;
    float x0 = lg[0], x1 = lg[1], x2 = lg[2];
    float m = fmaxf(x0, fmaxf(x1, x2));
    float lse = m + logf(expf(x0 - m) + expf(x1 - m) + expf(x2 - m));
    vv[0][p] = x2 - lse;  // don
    vv[1][p] = x1 - lse;  // acc
  }
  if (tid < 128) present[tid] = 0;
  __syncthreads();

  for (int sel = 0; sel < 2; ++sel) {
    for (int t = 0; t < TOP_N; ++t) {
      float bv = -INFINITY;
      int bi = 0x7fffffff;
      for (int p = tid; p < NREG; p += 1024) {
        float x = vv[sel][p];
        if (x > bv || (x == bv && p < bi)) { bv = x; bi = p; }
      }
#pragma unroll
      for (int off = 32; off; off >>= 1) {
        float ov = __shfl_xor(bv, off, 64);
        int oi = __shfl_xor(bi, off, 64);
        if (ov > bv || (ov == bv && oi < bi)) { bv = ov; bi = oi; }
      }
      if ((tid & 63) == 0) { wred[tid >> 6] = bv; wredi[tid >> 6] = bi; }
      __syncthreads();
      if (tid < 64) {
        bv = (tid < 16) ? wred[tid] : -INFINITY;
        bi = (tid < 16) ? wredi[tid] : 0x7fffffff;
#pragma unroll
        for (int off = 8; off; off >>= 1) {
          float ov = __shfl_xor(bv, off, 64);
          int oi = __shfl_xor(bi, off, 64);
          if (ov > bv || (ov == bv && oi < bi)) { bv = ov; bi = oi; }
        }
        if (tid == 0) {
          centers[sel * TOP_N + t] = LS + bi;
          vv[sel][bi] = -INFINITY;
        }
      }
      __syncthreads();
    }
  }

  for (int j = tid; j < Q_MAX; j += 1024) {
    int c = centers[j / (2 * R + 1)];
    int off = j % (2 * R + 1) - R;
    int v = c + off;
    v = v < 0 ? 0 : (v > L - 1 ? L - 1 : v);
    atomicOr(&present[v >> 5], 1u << (v & 31));
  }
  __syncthreads();

  int cnt = (tid < 128) ? __popc(present[tid]) : 0;
  if (tid < 128) {
    int x = cnt;
#pragma unroll
    for (int off = 1; off < 64; off <<= 1) {
      int o = __shfl_up(x, off, 64);
      if ((tid & 63) >= off) x += o;
    }
    if ((tid & 63) == 63) wtot[tid >> 6] = x;
    offs[tid] = x - cnt;
  }
  __syncthreads();
  int total = wtot[0] + wtot[1];
  if (tid < 128) {
    int base = offs[tid] + ((tid >= 64) ? wtot[0] : 0);
    unsigned mword = present[tid];
    while (mword) {
      int i = __ffs(mword) - 1;
      mword &= mword - 1;
      idx_out[b * Q_MAX + base] = tid * 32 + i;
      mask_out[b * Q_MAX + base] = 1;
      ++base;
    }
  }
  for (int j = total + tid; j < Q_MAX; j += 1024) {
    idx_out[b * Q_MAX + j] = L;
    mask_out[b * Q_MAX + j] = 0;
  }
}

// ---------------------------------------------------------------------------
__global__ __launch_bounds__(256) void gather_kernel(
    const float* __restrict__ enc, const int* __restrict__ idx,
    float* __restrict__ q_stream) {
  int row = blockIdx.x;
  int b = row / Q_MAX;
  int p = idx[row];
  float v = 0.f;
  if (p < L) v = enc[((long)b * L + p) * D + threadIdx.x];
  q_stream[(long)row * D + threadIdx.x] = v;
}

// ---------------------------------------------------------------------------
__global__ __launch_bounds__(256) void ln_bf16(
    const float* __restrict__ in, u16* __restrict__ out,
    const float* __restrict__ gg, const float* __restrict__ bb) {
  long row = blockIdx.x;
  int tid = threadIdx.x;
  float x = in[row * D + tid];
  float s1 = x, s2 = x * x;
#pragma unroll
  for (int off = 32; off; off >>= 1) {
    s1 += __shfl_xor(s1, off, 64);
    s2 += __shfl_xor(s2, off, 64);
  }
  __shared__ float p1[4], p2[4];
  int w = tid >> 6;
  if ((tid & 63) == 0) { p1[w] = s1; p2[w] = s2; }
  __syncthreads();
  s1 = p1[0] + p1[1] + p1[2] + p1[3];
  s2 = p2[0] + p2[1] + p2[2] + p2[3];
  float mean = s1 * (1.f / D);
  float var = fmaxf(s2 * (1.f / D) - mean * mean, 0.f);
  float r = rsqrtf(var + 1e-5f);
  out[row * D + tid] = f2bs((x - mean) * r * gg[tid] + bb[tid]);
}

__global__ __launch_bounds__(256) void ln_kv2(
    const float* __restrict__ in, u16* __restrict__ o0, u16* __restrict__ o1,
    const float* __restrict__ g) {
  long row = blockIdx.x;
  int tid = threadIdx.x;
  float x = in[row * D + tid];
  float s1 = x, s2 = x * x;
#pragma unroll
  for (int off = 32; off; off >>= 1) {
    s1 += __shfl_xor(s1, off, 64);
    s2 += __shfl_xor(s2, off, 64);
  }
  __shared__ float p1[4], p2[4];
  int w = tid >> 6;
  if ((tid & 63) == 0) { p1[w] = s1; p2[w] = s2; }
  __syncthreads();
  s1 = p1[0] + p1[1] + p1[2] + p1[3];
  s2 = p2[0] + p2[1] + p2[2] + p2[3];
  float mean = s1 * (1.f / D);
  float var = fmaxf(s2 * (1.f / D) - mean * mean, 0.f);
  float r = rsqrtf(var + 1e-5f);
  float xn = (x - mean) * r;
  o0[row * D + tid] = f2bs(xn * g[tid] + g[2 * D + tid]);
  o1[row * D + tid] = f2bs(xn * g[D + tid] + g[3 * D + tid]);
}

__global__ __launch_bounds__(256) void pack_lnkv(
    const float* __restrict__ g, const float* __restrict__ bb,
    float* __restrict__ dst) {
  int t = blockIdx.x * 256 + threadIdx.x;
  if (t < 2 * D) dst[t] = g[t];
  else if (t < 4 * D) dst[t] = bb[t - 2 * D];
}

// ---------------------------------------------------------------------------
__global__ __launch_bounds__(256) void transpose_all(
    const float* __restrict__ Wq_, const float* __restrict__ Wk_,
    const float* __restrict__ Wv_, const float* __restrict__ Wo_,
    const float* __restrict__ W1_, const float* __restrict__ W2_,
    u16* __restrict__ WT) {
  const long DD = (long)D * D, DFF = (long)D * FF;
  const long LSTR = 4 * DD + 2 * DFF;
  long t = (long)blockIdx.x * 256 + threadIdx.x;
  if (t >= NL * LSTR) return;
  int l = (int)(t / LSTR);
  long r = t - (long)l * LSTR;
  const float* src;
  long dstbase, e;
  int K_, N_;
  if (r < 4 * DD) {
    int which = (int)(r >> 16);
    e = r & (DD - 1);
    K_ = D; N_ = D;
    src = (which == 0 ? Wk_ : which == 1 ? Wv_ : which == 2 ? Wq_ : Wo_) +
          (long)l * DD;
    dstbase = l * LSTR + which * DD;
  } else if (r < 4 * DD + DFF) {
    e = r - 4 * DD;
    K_ = D; N_ = FF;
    src = W1_ + (long)l * DFF;
    dstbase = l * LSTR + 4 * DD;
  } else {
    e = r - 4 * DD - DFF;
    K_ = FF; N_ = D;
    src = W2_ + (long)l * DFF;
    dstbase = l * LSTR + 4 * DD + DFF;
  }
  int k = (int)(e / N_), n = (int)(e % N_);
  WT[dstbase + (long)n * K_ + k] = f2bs(src[e]);
}

// ---------------------------------------------------------------------------
// bf16 MFMA GEMM (64x64 tile, BK=32, 4 waves).
// EPI 0: bias->bf16; 1: gelu->bf16; 2: resid+mask->f32
// ---------------------------------------------------------------------------
template <int EPI>
__global__ __launch_bounds__(256) void gemm_mfma(
    const u16* __restrict__ A, const u16* __restrict__ BT,
    const float* __restrict__ bias, void* __restrict__ Cv,
    const float* __restrict__ resid, const int* __restrict__ mask, int M,
    int N, int K) {
  __shared__ short As[64][40];
  __shared__ short Bs[64][40];
  int bm = blockIdx.y * 64, bn = blockIdx.x * 64;
  int tid = threadIdx.x;
  int lane = tid & 63, w = tid >> 6;
  int g = lane >> 4, li = lane & 15;
  int wr = w >> 1, wc = w & 1;
  f32x4 acc[2][2] = {};

  int srow = tid >> 2, skc = (tid & 3) * 8;
  for (int k0 = 0; k0 < K; k0 += 32) {
    {
      int grow = bm + srow;
      bf16x8 av = {};
      if (grow < M)
        av = *reinterpret_cast<const bf16x8*>(A + (long)grow * K + k0 + skc);
      *reinterpret_cast<bf16x8*>(&As[srow][skc]) = av;
      bf16x8 bv = *reinterpret_cast<const bf16x8*>(
          BT + (long)(bn + srow) * K + k0 + skc);
      *reinterpret_cast<bf16x8*>(&Bs[srow][skc]) = bv;
    }
    __syncthreads();
    bf16x8 a0 = *reinterpret_cast<const bf16x8*>(&As[wr * 32 + li][g * 8]);
    bf16x8 a1 = *reinterpret_cast<const bf16x8*>(&As[wr * 32 + 16 + li][g * 8]);
    bf16x8 b0 = *reinterpret_cast<const bf16x8*>(&Bs[wc * 32 + li][g * 8]);
    bf16x8 b1 = *reinterpret_cast<const bf16x8*>(&Bs[wc * 32 + 16 + li][g * 8]);
    acc[0][0] = __builtin_amdgcn_mfma_f32_16x16x32_bf16(a0, b0, acc[0][0], 0, 0, 0);
    acc[0][1] = __builtin_amdgcn_mfma_f32_16x16x32_bf16(a0, b1, acc[0][1], 0, 0, 0);
    acc[1][0] = __builtin_amdgcn_mfma_f32_16x16x32_bf16(a1, b0, acc[1][0], 0, 0, 0);
    acc[1][1] = __builtin_amdgcn_mfma_f32_16x16x32_bf16(a1, b1, acc[1][1], 0, 0, 0);
    __syncthreads();
  }

#pragma unroll
  for (int mr = 0; mr < 2; ++mr)
#pragma unroll
    for (int nr = 0; nr < 2; ++nr)
#pragma unroll
      for (int r = 0; r < 4; ++r) {
        int row = bm + wr * 32 + mr * 16 + g * 4 + r;
        int col = bn + wc * 32 + nr * 16 + li;
        if (row >= M) continue;
        float v = acc[mr][nr][r] + bias[col];
        if (EPI == 1) v = gelu_exact(v);
        if (EPI == 2) {
          v += resid[(long)row * N + col];
          v = mask[row] ? v : 0.f;
          ((float*)Cv)[(long)row * N + col] = v;
        } else {
          ((u16*)Cv)[(long)row * N + col] = f2bs(v);
        }
      }
}

// ---------------------------------------------------------------------------
// Fused K+V projection GEMM: A = kv_ln [8192x256], BT = [WkT; WvT] (512x256).
// bn < 256 -> Kh[b][h][key][dchunk ^ ((key>>1)&3)]   (swizzled 16B chunks)
// bn >= 256 -> Vh[b][h][key/32][d][kchunk ^ ((d>>1)&6)] (swizzled 8B chunks)
// Swizzles make the attention LDS fragment reads bank-conflict-free; the
// attn kernel applies the SAME XOR on its read offsets (values unchanged).
// ---------------------------------------------------------------------------
__global__ __launch_bounds__(256) void gemm_kv(
    const u16* __restrict__ A, const u16* __restrict__ BT,
    const float* __restrict__ biasK, const float* __restrict__ biasV,
    u16* __restrict__ Kh, u16* __restrict__ Vh) {
  __shared__ short As[64][40];
  __shared__ short Bs[64][40];
  int bm = blockIdx.y * 64, bn = blockIdx.x * 64;
  int tid = threadIdx.x;
  int lane = tid & 63, w = tid >> 6;
  int g = lane >> 4, li = lane & 15;
  int wr = w >> 1, wc = w & 1;
  f32x4 acc[2][2] = {};

  int srow = tid >> 2, skc = (tid & 3) * 8;
  for (int k0 = 0; k0 < D; k0 += 32) {
    {
      bf16x8 av = *reinterpret_cast<const bf16x8*>(
          A + (long)(bm + srow) * D + k0 + skc);
      *reinterpret_cast<bf16x8*>(&As[srow][skc]) = av;
      bf16x8 bv = *reinterpret_cast<const bf16x8*>(
          BT + (long)(bn + srow) * D + k0 + skc);
      *reinterpret_cast<bf16x8*>(&Bs[srow][skc]) = bv;
    }
    __syncthreads();
    bf16x8 a0 = *reinterpret_cast<const bf16x8*>(&As[wr * 32 + li][g * 8]);
    bf16x8 a1 = *reinterpret_cast<const bf16x8*>(&As[wr * 32 + 16 + li][g * 8]);
    bf16x8 b0 = *reinterpret_cast<const bf16x8*>(&Bs[wc * 32 + li][g * 8]);
    bf16x8 b1 = *reinterpret_cast<const bf16x8*>(&Bs[wc * 32 + 16 + li][g * 8]);
    acc[0][0] = __builtin_amdgcn_mfma_f32_16x16x32_bf16(a0, b0, acc[0][0], 0, 0, 0);
    acc[0][1] = __builtin_amdgcn_mfma_f32_16x16x32_bf16(a0, b1, acc[0][1], 0, 0, 0);
    acc[1][0] = __builtin_amdgcn_mfma_f32_16x16x32_bf16(a1, b0, acc[1][0], 0, 0, 0);
    acc[1][1] = __builtin_amdgcn_mfma_f32_16x16x32_bf16(a1, b1, acc[1][1], 0, 0, 0);
    __syncthreads();
  }

  if (bn < 256) {
    __shared__ u16 Ct[64][72];
#pragma unroll
    for (int mr = 0; mr < 2; ++mr)
#pragma unroll
      for (int nr = 0; nr < 2; ++nr)
#pragma unroll
        for (int r = 0; r < 4; ++r) {
          int rowL = wr * 32 + mr * 16 + g * 4 + r;
          int colL = wc * 32 + nr * 16 + li;
          Ct[rowL][colL] = f2bs(acc[mr][nr][r] + biasK[bn + colL]);
        }
    __syncthreads();
#pragma unroll
    for (int p = 0; p < 2; ++p) {
      int rowL = (tid >> 3) + p * 32;
      int c8 = (tid & 7) * 8;
      int grow = bm + rowL;
      int b2 = grow >> 12, key = grow & (L - 1);
      int gcol = bn + c8;
      int hh = gcol >> 5, dd = gcol & (HD - 1);
      int cst = (dd >> 3) ^ ((key >> 1) & 3);  // swizzled 16B chunk slot
      u16* dst = Kh + (((long)(b2 * H + hh) * L + key) * 32 + (cst << 3));
      *reinterpret_cast<bf16x8*>(dst) =
          *reinterpret_cast<const bf16x8*>(&Ct[rowL][c8]);
    }
  } else {
    int vbn = bn - 256;
    __shared__ u16 Ct[64][72];
#pragma unroll
    for (int mr = 0; mr < 2; ++mr)
#pragma unroll
      for (int nr = 0; nr < 2; ++nr)
#pragma unroll
        for (int r = 0; r < 4; ++r) {
          int rowL = wr * 32 + mr * 16 + g * 4 + r;
          int colL = wc * 32 + nr * 16 + li;
          Ct[colL][rowL] = f2bs(acc[mr][nr][r] + biasV[vbn + colL]);
        }
    __syncthreads();
    int b2 = bm >> 12;
#pragma unroll
    for (int p = 0; p < 2; ++p) {
      int colL = (tid >> 3) + p * 32;
      int rem = tid & 7;
      int kb = rem >> 2, k8 = (rem & 3) * 8;
      int gcol = vbn + colL;
      int hh = gcol >> 5, dd = gcol & (HD - 1);
      int kb32 = ((bm & (L - 1)) >> 5) + kb;
      int j = (k8 >> 2) ^ ((dd >> 1) & 6);  // swizzled 8B-chunk pair slot
      u16* dst = Vh + (((long)(b2 * H + hh) * (L / 32) + kb32) * 1024 +
                       dd * 32 + (j << 2));
      *reinterpret_cast<bf16x8*>(dst) =
          *reinterpret_cast<const bf16x8*>(&Ct[colL][kb * 32 + k8]);
    }
  }
}

// ---------------------------------------------------------------------------
// Fused flash attention: 512 threads = 8 split-K waves per (b,h,32-q tile).
// Wave-private LDS double-buffer via global_load_lds DMA (no barriers in the
// loop, counted vmcnt). Kh/Vh carry an XOR swizzle in global so the linear
// DMA lands conflict-free for the fragment reads (read offsets apply the
// same XOR). No-max exp2 softmax -> plain-sum split-K combine. XCD swizzle.
// ---------------------------------------------------------------------------
__global__ __launch_bounds__(512) void attn_mfma(
    const u16* __restrict__ Qb, const u16* __restrict__ Kh,
    const u16* __restrict__ Vh, u16* __restrict__ AO) {
  __shared__ alignas(16) char pool[NSPLIT * 8192];  // 64 KB
  int i = blockIdx.x;
  int xcd = i & 7, slot = i >> 3;          // 66 slots per XCD
  int bh = (xcd << 1) | (slot >= NQT ? 1 : 0);
  int qt = (slot >= NQT) ? slot - NQT : slot;
  int h = bh & 7;
  int b = bh >> 3;
  int tid = threadIdx.x, w = tid >> 6, lane = tid & 63;
  int g = lane >> 4, li = lane & 15;

  fr qf0, qf1;
  {
    const float QSC = 0.25509836048f;  // (1/sqrt(32)) * log2(e)
#pragma unroll
    for (int qb = 0; qb < 2; ++qb) {
      int qrow = qt * 32 + qb * 16 + li;
      if (qrow >= Q_MAX) qrow = Q_MAX - 1;
      bf16x8 raw = *reinterpret_cast<const bf16x8*>(
          Qb + ((long)(b * Q_MAX + qrow)) * D + h * HD + g * 8);
      fr& qf = qb ? qf1 : qf0;
#pragma unroll
      for (int j = 0; j < 4; ++j)
        qf.i[j] = (int)cvt_pk(bs2f((u16)raw[2 * j]) * QSC,
                              bs2f((u16)raw[2 * j + 1]) * QSC);
    }
  }

  f32x4 acc00 = {}, acc01 = {}, acc10 = {}, acc11 = {};
  float den0 = 0.f, den1 = 0.f;
  const f32x4 z = {};

  const u16* kbase = Kh + ((long)(b * H + h) * L) * HD;
  const u16* vbase = Vh + ((long)(b * H + h) * L) * HD;
  int kstart = w * KCHUNK;
  char* wbase = pool + w * 8192;  // wave-private: 2 bufs x (2KB K + 2KB V)

  // swizzled LDS read offsets (u16 units); key%8 and d determine the XOR
  int s_li = (li >> 1) & 3;
  int t_li = (li >> 1) & 6;
  int kof0 = li * 32 + ((g ^ s_li) << 3);
  int kof1 = (16 + li) * 32 + ((g ^ s_li) << 3);
  int va0o = li * 32 + ((g ^ t_li) << 2);
  int vb0o = li * 32 + (((4 + g) ^ t_li) << 2);
  int va1o = (16 + li) * 32 + ((g ^ t_li) << 2);
  int vb1o = (16 + li) * 32 + (((4 + g) ^ t_li) << 2);

  // prologue: stage tile 0 into buf 0
  {
    const u16* ks = kbase + (long)kstart * HD + lane * 8;
    const u16* vs = vbase + (long)kstart * HD + lane * 8;
    u16* lk = (u16*)wbase;
    GLL16(ks, lk);
    GLL16(ks + 512, lk + 512);
    GLL16(vs, lk + 1024);
    GLL16(vs + 512, lk + 1536);
  }

  for (int t = 0; t < NT; ++t) {
    char* cbuf = wbase + (t & 1) * 4096;
    if (t + 1 < NT) {
      char* nbuf = wbase + ((t + 1) & 1) * 4096;
      const u16* ks = kbase + (long)(kstart + (t + 1) * 32) * HD + lane * 8;
      const u16* vs = vbase + (long)(kstart + (t + 1) * 32) * HD + lane * 8;
      u16* lk = (u16*)nbuf;
      GLL16(ks, lk);
      GLL16(ks + 512, lk + 512);
      GLL16(vs, lk + 1024);
      GLL16(vs + 512, lk + 1536);
      asm volatile("s_waitcnt vmcnt(4)" ::: "memory");
    } else {
      asm volatile("s_waitcnt vmcnt(0)" ::: "memory");
    }
    __builtin_amdgcn_sched_barrier(0);

    const u16* kl = (const u16*)cbuf;
    const u16* vl = kl + 1024;
    bf16x8 kf0 = *reinterpret_cast<const bf16x8*>(kl + kof0);
    bf16x8 kf1 = *reinterpret_cast<const bf16x8*>(kl + kof1);
    uint2 va0 = *reinterpret_cast<const uint2*>(vl + va0o);
    uint2 vb0 = *reinterpret_cast<const uint2*>(vl + vb0o);
    uint2 va1 = *reinterpret_cast<const uint2*>(vl + va1o);
    uint2 vb1 = *reinterpret_cast<const uint2*>(vl + vb1o);

    f32x4 s00 = __builtin_amdgcn_mfma_f32_16x16x32_bf16(kf0, qf0.h, z, 0, 0, 0);
    f32x4 s10 = __builtin_amdgcn_mfma_f32_16x16x32_bf16(kf1, qf0.h, z, 0, 0, 0);
    f32x4 s01 = __builtin_amdgcn_mfma_f32_16x16x32_bf16(kf0, qf1.h, z, 0, 0, 0);
    f32x4 s11 = __builtin_amdgcn_mfma_f32_16x16x32_bf16(kf1, qf1.h, z, 0, 0, 0);

    float p00[4], p10[4], p01[4], p11[4];
#pragma unroll
    for (int r = 0; r < 4; ++r) {
      p00[r] = exp2f(s00[r]);
      p10[r] = exp2f(s10[r]);
      p01[r] = exp2f(s01[r]);
      p11[r] = exp2f(s11[r]);
      den0 += p00[r] + p10[r];
      den1 += p01[r] + p11[r];
    }
    fr pf0, pf1;
    pf0.i[0] = (int)cvt_pk(p00[0], p00[1]);
    pf0.i[1] = (int)cvt_pk(p00[2], p00[3]);
    pf0.i[2] = (int)cvt_pk(p10[0], p10[1]);
    pf0.i[3] = (int)cvt_pk(p10[2], p10[3]);
    pf1.i[0] = (int)cvt_pk(p01[0], p01[1]);
    pf1.i[1] = (int)cvt_pk(p01[2], p01[3]);
    pf1.i[2] = (int)cvt_pk(p11[0], p11[1]);
    pf1.i[3] = (int)cvt_pk(p11[2], p11[3]);

    fr v0, v1;
    v0.i = (i32x4){(int)va0.x, (int)va0.y, (int)vb0.x, (int)vb0.y};
    v1.i = (i32x4){(int)va1.x, (int)va1.y, (int)vb1.x, (int)vb1.y};
    acc00 = __builtin_amdgcn_mfma_f32_16x16x32_bf16(v0.h, pf0.h, acc00, 0, 0, 0);
    acc01 = __builtin_amdgcn_mfma_f32_16x16x32_bf16(v0.h, pf1.h, acc01, 0, 0, 0);
    acc10 = __builtin_amdgcn_mfma_f32_16x16x32_bf16(v1.h, pf0.h, acc10, 0, 0, 0);
    acc11 = __builtin_amdgcn_mfma_f32_16x16x32_bf16(v1.h, pf1.h, acc11, 0, 0, 0);
  }

  // reduce per-lane denominators over g
  den0 += __shfl_xor(den0, 16, 64);
  den0 += __shfl_xor(den0, 32, 64);
  den1 += __shfl_xor(den1, 16, 64);
  den1 += __shfl_xor(den1, 32, 64);

  // combine: overlay staging LDS (all waves done with it after barrier)
  __syncthreads();
  float (*accs)[32][33] = (float(*)[32][33])pool;
  float (*dsh)[32] = (float(*)[32])(pool + NSPLIT * 32 * 33 * 4);
#pragma unroll
  for (int r = 0; r < 4; ++r) {
    accs[w][g * 4 + r][li] = acc00[r];
    accs[w][g * 4 + r][16 + li] = acc01[r];
    accs[w][16 + g * 4 + r][li] = acc10[r];
    accs[w][16 + g * 4 + r][16 + li] = acc11[r];
  }
  if (g == 0) {
    dsh[w][li] = den0;
    dsh[w][16 + li] = den1;
  }
  __syncthreads();

  int q = tid >> 4, dp = tid & 15;  // q 0..31, d-pair 0..15
  float Den = 0.f, o0 = 0.f, o1 = 0.f;
#pragma unroll
  for (int ww = 0; ww < NSPLIT; ++ww) {
    Den += dsh[ww][q];
    o0 += accs[ww][2 * dp][q];
    o1 += accs[ww][2 * dp + 1][q];
  }
  float inv = 1.f / Den;
  int qrow = qt * 32 + q;
  if (qrow < Q_MAX) {
    unsigned pk = cvt_pk(o0 * inv, o1 * inv);
    *reinterpret_cast<unsigned*>(
        AO + ((long)(b * Q_MAX + qrow)) * D + h * HD + 2 * dp) = pk;
  }
}

// ---------------------------------------------------------------------------
__global__ __launch_bounds__(256) void head_kernel(
    const float* __restrict__ enc, const float* __restrict__ hW,
    const float* __restrict__ hb, float* __restrict__ out) {
  int row = blockIdx.x * 4 + (threadIdx.x >> 6);
  int lane = threadIdx.x & 63;
  const float4 a = *reinterpret_cast<const float4*>(enc + (long)row * D + lane * 4);
  float c0 = 0.f, c1 = 0.f, c2 = 0.f;
  const float av[4] = {a.x, a.y, a.z, a.w};
#pragma unroll
  for (int i = 0; i < 4; ++i) {
    int k = lane * 4 + i;
    c0 += av[i] * hW[k * 3];
    c1 += av[i] * hW[k * 3 + 1];
    c2 += av[i] * hW[k * 3 + 2];
  }
#pragma unroll
  for (int off = 32; off; off >>= 1) {
    c0 += __shfl_down(c0, off, 64);
    c1 += __shfl_down(c1, off, 64);
    c2 += __shfl_down(c2, off, 64);
  }
  if (lane == 0) {
    out[(long)row * 3] = c0 + hb[0];
    out[(long)row * 3 + 1] = c1 + hb[1];
    out[(long)row * 3 + 2] = c2 + hb[2];
  }
}

// ---------------------------------------------------------------------------
__global__ __launch_bounds__(64) void overwrite_kernel(
    const float* __restrict__ q_stream, const int* __restrict__ idx,
    const int* __restrict__ mask, const float* __restrict__ hW,
    const float* __restrict__ hb, float* __restrict__ out) {
  int j = blockIdx.x;
  if (!mask[j]) return;
  int b = j / Q_MAX;
  int p = idx[j];
  int lane = threadIdx.x;
  const float* a = q_stream + (long)j * D;
  float a0 = a[lane], a1 = a[lane + 64], a2 = a[lane + 128],
        a3 = a[lane + 192];
  for (int c = 0; c < 3; ++c) {
    float s = a0 * hW[lane * 3 + c] + a1 * hW[(lane + 64) * 3 + c] +
              a2 * hW[(lane + 128) * 3 + c] + a3 * hW[(lane + 192) * 3 + c];
    for (int off = 32; off > 0; off >>= 1) s += __shfl_down(s, off, 64);
    if (lane == 0) out[((long)b * L + p) * 3 + c] = s + hb[c];
  }
}

// ---------------------------------------------------------------------------
extern "C" void kernel_launch(void* const* d_in, const int* in_sizes, int n_in,
                              void* d_out, int out_size, void* d_ws,
                              size_t ws_size, hipStream_t stream) {
  const float* enc = (const float*)d_in[0];
  const float* clog = (const float*)d_in[1];
  const float* ln_q_g = (const float*)d_in[2];
  const float* ln_q_b = (const float*)d_in[3];
  const float* ln_kv_g = (const float*)d_in[4];
  const float* ln_kv_b = (const float*)d_in[5];
  const float* Wq = (const float*)d_in[6];
  const float* bq = (const float*)d_in[7];
  const float* Wk = (const float*)d_in[8];
  const float* bk = (const float*)d_in[9];
  const float* Wv = (const float*)d_in[10];
  const float* bv = (const float*)d_in[11];
  const float* Wo = (const float*)d_in[12];
  const float* bo = (const float*)d_in[13];
  const float* ffn_g = (const float*)d_in[14];
  const float* ffn_b = (const float*)d_in[15];
  const float* W1 = (const float*)d_in[16];
  const float* b1 = (const float*)d_in[17];
  const float* W2 = (const float*)d_in[18];
  const float* b2 = (const float*)d_in[19];
  const float* head_W = (const float*)d_in[20];
  const float* head_b = (const float*)d_in[21];
  float* out = (float*)d_out;

  char* ws = (char*)d_ws;
  float* q_stream = (float*)ws;            ws += (long)QROWS * D * 4;
  u16* kvl0 = (u16*)ws;                    ws += (long)KVROWS * D * 2;
  u16* kvl1 = (u16*)ws;                    ws += (long)KVROWS * D * 2;
  u16* Khbuf = (u16*)ws;                   ws += (long)B * H * L * HD * 2;
  u16* Vhbuf = (u16*)ws;                   ws += (long)B * H * L * HD * 2;
  u16* q_ln = (u16*)ws;                    ws += (long)QROWS * D * 2;
  u16* Qbuf = (u16*)ws;                    ws += (long)QROWS * D * 2;
  u16* AObuf = (u16*)ws;                   ws += (long)QROWS * D * 2;
  u16* H1buf = (u16*)ws;                   ws += (long)QROWS * FF * 2;
  u16* WT = (u16*)ws;                      ws += (long)NL * (4 * D * D + 2 * D * FF) * 2;
  float* lnkv_pack = (float*)ws;           ws += 4 * D * 4;
  int* idxbuf = (int*)ws;                  ws += QROWS * 4;
  int* maskbuf = (int*)ws;

  const long DD = (long)D * D, DFF = (long)D * FF;
  const long LSTR = 4 * DD + 2 * DFF;

  transpose_all<<<(int)((NL * LSTR + 255) / 256), 256, 0, stream>>>(
      Wq, Wk, Wv, Wo, W1, W2, WT);
  pack_lnkv<<<(4 * D + 255) / 256, 256, 0, stream>>>(ln_kv_g, ln_kv_b, lnkv_pack);
  ln_kv2<<<KVROWS, 256, 0, stream>>>(enc, kvl0, kvl1, lnkv_pack);
  select_kernel<<<B, 1024, 0, stream>>>(clog, idxbuf, maskbuf);
  gather_kernel<<<QROWS, 256, 0, stream>>>(enc, idxbuf, q_stream);

  for (int l = 0; l < NL; ++l) {
    u16* base = WT + l * LSTR;
    u16* kv_ln = (l == 0) ? kvl0 : kvl1;

    ln_bf16<<<QROWS, 256, 0, stream>>>(q_stream, q_ln, ln_q_g + l * D, ln_q_b + l * D);

    dim3 gKV(512 / 64, KVROWS / 64);
    gemm_kv<<<gKV, 256, 0, stream>>>(kv_ln, base, bk + l * D, bv + l * D,
                                     Khbuf, Vhbuf);
    dim3 gQ(D / 64, (QROWS + 63) / 64);
    gemm_mfma<0><<<gQ, 256, 0, stream>>>(q_ln, base + 2 * DD, bq + l * D,
                                         (void*)Qbuf, nullptr, nullptr,
                                         QROWS, D, D);

    attn_mfma<<<B * H * NQT, 512, 0, stream>>>(Qbuf, Khbuf, Vhbuf, AObuf);

    gemm_mfma<2><<<gQ, 256, 0, stream>>>(AObuf, base + 3 * DD, bo + l * D,
                                         (void*)q_stream, q_stream, maskbuf,
                                         QROWS, D, D);

    ln_bf16<<<QROWS, 256, 0, stream>>>(q_stream, q_ln, ffn_g + l * D, ffn_b + l * D);
    dim3 gF1(FF / 64, (QROWS + 63) / 64);
    gemm_mfma<1><<<gF1, 256, 0, stream>>>(q_ln, base + 4 * DD, b1 + l * FF,
                                          (void*)H1buf, nullptr, nullptr,
                                          QROWS, FF, D);
    dim3 gF2(D / 64, (QROWS + 63) / 64);
    gemm_mfma<2><<<gF2, 256, 0, stream>>>(H1buf, base + 4 * DD + DFF,
                                          b2 + l * D, (void*)q_stream,
                                          q_stream, maskbuf, QROWS, D, FF);
  }

  head_kernel<<<KVROWS / 4, 256, 0, stream>>>(enc, head_W, head_b, out);
  overwrite_kernel<<<QROWS, 64, 0, stream>>>(q_stream, idxbuf, maskbuf, head_W,
                                             head_b, out);
}

// Round 11
// 240.996 us; speedup vs baseline: 1.4308x; 1.0464x over previous
//
#include <hip/hip_runtime.h>
#include <cmath>

constexpr int B = 2, L = 4096, D = 256, H = 8, NC = 3;
constexpr int TOP_N = 8, R = 32;
constexpr int LS = 1000, LE = 3000;
constexpr int NL = 2;
constexpr int FF = 4 * D;                        // 1024
constexpr int Q_MAX = 2 * TOP_N * (2 * R + 1);   // 1040
constexpr int HD = D / H;                        // 32
constexpr int QROWS = B * Q_MAX;                 // 2080
constexpr int KVROWS = B * L;                    // 8192
constexpr int NQT = (Q_MAX + 31) / 32;           // 33 q-tiles of 32
constexpr int NREG = LE - LS;                    // 2000
constexpr int NSPLIT = 8;                        // split-K waves per block
constexpr int KCHUNK = L / NSPLIT;               // 512 keys per wave
constexpr int NT = KCHUNK / 32;                  // 16 iterations

typedef __attribute__((ext_vector_type(8))) short bf16x8;
typedef __attribute__((ext_vector_type(4))) float f32x4;
typedef __attribute__((ext_vector_type(4))) int i32x4;
typedef unsigned short u16;

union fr {
  bf16x8 h;
  i32x4 i;
};

__device__ __forceinline__ u16 f2bs(float f) {
  unsigned int u = __float_as_uint(f);
  unsigned int r = u + 0x7fffu + ((u >> 16) & 1u);
  return (u16)(r >> 16);
}
__device__ __forceinline__ float bs2f(u16 s) {
  return __uint_as_float(((unsigned int)s) << 16);
}
__device__ __forceinline__ float gelu_exact(float x) {
  return 0.5f * x * (1.f + erff(x * 0.70710678118654752440f));
}
__device__ __forceinline__ unsigned cvt_pk(float lo, float hi) {
  unsigned r;
  asm("v_cvt_pk_bf16_f32 %0, %1, %2" : "=v"(r) : "v"(lo), "v"(hi));
  return r;
}

#define GLL16(gsrc, ldst)                                                   \
  __builtin_amdgcn_global_load_lds(                                         \
      (const __attribute__((address_space(1))) unsigned int*)(gsrc),        \
      (__attribute__((address_space(3))) unsigned int*)(ldst), 16, 0, 0)

// ---------------------------------------------------------------------------
// Vicinity selection. One 1024-thread block per batch.
// ---------------------------------------------------------------------------
__global__ __launch_bounds__(1024) void select_kernel(
    const float* __restrict__ logits, int* __restrict__ idx_out,
    int* __restrict__ mask_out) {
  int b = blockIdx.x;
  int tid = threadIdx.x;
  __shared__ float vv[2][NREG];
  __shared__ int centers[2 * TOP_N];
  __shared__ unsigned present[L / 32];
  __shared__ float wred[16];
  __shared__ int wredi[16];
  __shared__ int offs[128];
  __shared__ int wtot[2];

  for (int p = tid; p < NREG; p += 1024) {
    const float* lg = logits + ((long)b * L + LS + p) * NC;
    float x0 = lg[0], x1 = lg[1], x2 = lg[2];
    float m = fmaxf(x0, fmaxf(x1, x2));
    float lse = m + logf(expf(x0 - m) + expf(x1 - m) + expf(x2 - m));
    vv[0][p] = x2 - lse;  // don
    vv[1][p] = x1 - lse;  // acc
  }
  if (tid < 128) present[tid] = 0;
  __syncthreads();

  for (int sel = 0; sel < 2; ++sel) {
    for (int t = 0; t < TOP_N; ++t) {
      float bv = -INFINITY;
      int bi = 0x7fffffff;
      for (int p = tid; p < NREG; p += 1024) {
        float x = vv[sel][p];
        if (x > bv || (x == bv && p < bi)) { bv = x; bi = p; }
      }
#pragma unroll
      for (int off = 32; off; off >>= 1) {
        float ov = __shfl_xor(bv, off, 64);
        int oi = __shfl_xor(bi, off, 64);
        if (ov > bv || (ov == bv && oi < bi)) { bv = ov; bi = oi; }
      }
      if ((tid & 63) == 0) { wred[tid >> 6] = bv; wredi[tid >> 6] = bi; }
      __syncthreads();
      if (tid < 64) {
        bv = (tid < 16) ? wred[tid] : -INFINITY;
        bi = (tid < 16) ? wredi[tid] : 0x7fffffff;
#pragma unroll
        for (int off = 8; off; off >>= 1) {
          float ov = __shfl_xor(bv, off, 64);
          int oi = __shfl_xor(bi, off, 64);
          if (ov > bv || (ov == bv && oi < bi)) { bv = ov; bi = oi; }
        }
        if (tid == 0) {
          centers[sel * TOP_N + t] = LS + bi;
          vv[sel][bi] = -INFINITY;
        }
      }
      __syncthreads();
    }
  }

  for (int j = tid; j < Q_MAX; j += 1024) {
    int c = centers[j / (2 * R + 1)];
    int off = j % (2 * R + 1) - R;
    int v = c + off;
    v = v < 0 ? 0 : (v > L - 1 ? L - 1 : v);
    atomicOr(&present[v >> 5], 1u << (v & 31));
  }
  __syncthreads();

  int cnt = (tid < 128) ? __popc(present[tid]) : 0;
  if (tid < 128) {
    int x = cnt;
#pragma unroll
    for (int off = 1; off < 64; off <<= 1) {
      int o = __shfl_up(x, off, 64);
      if ((tid & 63) >= off) x += o;
    }
    if ((tid & 63) == 63) wtot[tid >> 6] = x;
    offs[tid] = x - cnt;
  }
  __syncthreads();
  int total = wtot[0] + wtot[1];
  if (tid < 128) {
    int base = offs[tid] + ((tid >= 64) ? wtot[0] : 0);
    unsigned mword = present[tid];
    while (mword) {
      int i = __ffs(mword) - 1;
      mword &= mword - 1;
      idx_out[b * Q_MAX + base] = tid * 32 + i;
      mask_out[b * Q_MAX + base] = 1;
      ++base;
    }
  }
  for (int j = total + tid; j < Q_MAX; j += 1024) {
    idx_out[b * Q_MAX + j] = L;
    mask_out[b * Q_MAX + j] = 0;
  }
}

// ---------------------------------------------------------------------------
__global__ __launch_bounds__(256) void gather_kernel(
    const float* __restrict__ enc, const int* __restrict__ idx,
    float* __restrict__ q_stream) {
  int row = blockIdx.x;
  int b = row / Q_MAX;
  int p = idx[row];
  float v = 0.f;
  if (p < L) v = enc[((long)b * L + p) * D + threadIdx.x];
  q_stream[(long)row * D + threadIdx.x] = v;
}

// ---------------------------------------------------------------------------
__global__ __launch_bounds__(256) void ln_bf16(
    const float* __restrict__ in, u16* __restrict__ out,
    const float* __restrict__ gg, const float* __restrict__ bb) {
  long row = blockIdx.x;
  int tid = threadIdx.x;
  float x = in[row * D + tid];
  float s1 = x, s2 = x * x;
#pragma unroll
  for (int off = 32; off; off >>= 1) {
    s1 += __shfl_xor(s1, off, 64);
    s2 += __shfl_xor(s2, off, 64);
  }
  __shared__ float p1[4], p2[4];
  int w = tid >> 6;
  if ((tid & 63) == 0) { p1[w] = s1; p2[w] = s2; }
  __syncthreads();
  s1 = p1[0] + p1[1] + p1[2] + p1[3];
  s2 = p2[0] + p2[1] + p2[2] + p2[3];
  float mean = s1 * (1.f / D);
  float var = fmaxf(s2 * (1.f / D) - mean * mean, 0.f);
  float r = rsqrtf(var + 1e-5f);
  out[row * D + tid] = f2bs((x - mean) * r * gg[tid] + bb[tid]);
}

// LayerNorm of enc with BOTH layers' gamma/beta -> two bf16 outputs
__global__ __launch_bounds__(256) void ln_kv2(
    const float* __restrict__ in, u16* __restrict__ o0, u16* __restrict__ o1,
    const float* __restrict__ gg, const float* __restrict__ bb) {
  long row = blockIdx.x;
  int tid = threadIdx.x;
  float x = in[row * D + tid];
  float s1 = x, s2 = x * x;
#pragma unroll
  for (int off = 32; off; off >>= 1) {
    s1 += __shfl_xor(s1, off, 64);
    s2 += __shfl_xor(s2, off, 64);
  }
  __shared__ float p1[4], p2[4];
  int w = tid >> 6;
  if ((tid & 63) == 0) { p1[w] = s1; p2[w] = s2; }
  __syncthreads();
  s1 = p1[0] + p1[1] + p1[2] + p1[3];
  s2 = p2[0] + p2[1] + p2[2] + p2[3];
  float mean = s1 * (1.f / D);
  float var = fmaxf(s2 * (1.f / D) - mean * mean, 0.f);
  float r = rsqrtf(var + 1e-5f);
  float xn = (x - mean) * r;
  o0[row * D + tid] = f2bs(xn * gg[tid] + bb[tid]);
  o1[row * D + tid] = f2bs(xn * gg[D + tid] + bb[D + tid]);
}

// ---------------------------------------------------------------------------
// LDS-tiled weight transpose+bf16 (coalesced reads AND writes).
// 64x64 tiles; grid = NL * 192 blocks. WT layout unchanged:
// per layer: Wk[0], Wv[DD], Wq[2DD], Wo[3DD], W1[4DD], W2[4DD+DFF], [n][k].
// ---------------------------------------------------------------------------
__global__ __launch_bounds__(256) void transpose_tiled(
    const float* __restrict__ Wq_, const float* __restrict__ Wk_,
    const float* __restrict__ Wv_, const float* __restrict__ Wo_,
    const float* __restrict__ W1_, const float* __restrict__ W2_,
    u16* __restrict__ WT) {
  __shared__ u16 T[64][65];
  const long DD = (long)D * D, DFF = (long)D * FF;
  const long LSTR = 4 * DD + 2 * DFF;
  int t = blockIdx.x;
  int l = t / 192, r = t % 192;
  const float* src;
  long dbase;
  int K_, N_, kt, nt;
  if (r < 64) {
    int which = r >> 4, sub = r & 15;
    kt = sub >> 2;
    nt = sub & 3;
    K_ = 256;
    N_ = 256;
    src = (which == 0 ? Wk_ : which == 1 ? Wv_ : which == 2 ? Wq_ : Wo_) +
          (long)l * DD;
    dbase = (long)l * LSTR + (long)which * DD;
  } else if (r < 128) {
    int sub = r - 64;
    kt = sub >> 4;
    nt = sub & 15;
    K_ = 256;
    N_ = 1024;
    src = W1_ + (long)l * DFF;
    dbase = (long)l * LSTR + 4 * DD;
  } else {
    int sub = r - 128;
    kt = sub >> 2;
    nt = sub & 3;
    K_ = 1024;
    N_ = 256;
    src = W2_ + (long)l * DFF;
    dbase = (long)l * LSTR + 4 * DD + DFF;
  }
  int k0 = kt * 64, n0 = nt * 64;
  {
    int kr = threadIdx.x >> 2, c16 = (threadIdx.x & 3) * 16;
    const float* sp = src + (long)(k0 + kr) * N_ + n0 + c16;
#pragma unroll
    for (int i = 0; i < 4; ++i) {
      float4 v = *reinterpret_cast<const float4*>(sp + 4 * i);
      T[kr][c16 + 4 * i + 0] = f2bs(v.x);
      T[kr][c16 + 4 * i + 1] = f2bs(v.y);
      T[kr][c16 + 4 * i + 2] = f2bs(v.z);
      T[kr][c16 + 4 * i + 3] = f2bs(v.w);
    }
  }
  __syncthreads();
  {
    int nr = threadIdx.x >> 2, kc = (threadIdx.x & 3) * 16;
    u16 tmp[16];
#pragma unroll
    for (int j = 0; j < 16; ++j) tmp[j] = T[kc + j][nr];
    u16* dp = WT + dbase + (long)(n0 + nr) * K_ + k0 + kc;
    *reinterpret_cast<bf16x8*>(dp) = *reinterpret_cast<const bf16x8*>(&tmp[0]);
    *reinterpret_cast<bf16x8*>(dp + 8) =
        *reinterpret_cast<const bf16x8*>(&tmp[8]);
  }
}

// ---------------------------------------------------------------------------
// bf16 MFMA GEMM (64x64 tile, BK=32, 4 waves).
// EPI 0: bias->bf16; 1: gelu->bf16; 2: resid+mask->f32
// ---------------------------------------------------------------------------
template <int EPI>
__global__ __launch_bounds__(256) void gemm_mfma(
    const u16* __restrict__ A, const u16* __restrict__ BT,
    const float* __restrict__ bias, void* __restrict__ Cv,
    const float* __restrict__ resid, const int* __restrict__ mask, int M,
    int N, int K) {
  __shared__ short As[64][40];
  __shared__ short Bs[64][40];
  int bm = blockIdx.y * 64, bn = blockIdx.x * 64;
  int tid = threadIdx.x;
  int lane = tid & 63, w = tid >> 6;
  int g = lane >> 4, li = lane & 15;
  int wr = w >> 1, wc = w & 1;
  f32x4 acc[2][2] = {};

  int srow = tid >> 2, skc = (tid & 3) * 8;
  for (int k0 = 0; k0 < K; k0 += 32) {
    {
      int grow = bm + srow;
      bf16x8 av = {};
      if (grow < M)
        av = *reinterpret_cast<const bf16x8*>(A + (long)grow * K + k0 + skc);
      *reinterpret_cast<bf16x8*>(&As[srow][skc]) = av;
      bf16x8 bv = *reinterpret_cast<const bf16x8*>(
          BT + (long)(bn + srow) * K + k0 + skc);
      *reinterpret_cast<bf16x8*>(&Bs[srow][skc]) = bv;
    }
    __syncthreads();
    bf16x8 a0 = *reinterpret_cast<const bf16x8*>(&As[wr * 32 + li][g * 8]);
    bf16x8 a1 = *reinterpret_cast<const bf16x8*>(&As[wr * 32 + 16 + li][g * 8]);
    bf16x8 b0 = *reinterpret_cast<const bf16x8*>(&Bs[wc * 32 + li][g * 8]);
    bf16x8 b1 = *reinterpret_cast<const bf16x8*>(&Bs[wc * 32 + 16 + li][g * 8]);
    acc[0][0] = __builtin_amdgcn_mfma_f32_16x16x32_bf16(a0, b0, acc[0][0], 0, 0, 0);
    acc[0][1] = __builtin_amdgcn_mfma_f32_16x16x32_bf16(a0, b1, acc[0][1], 0, 0, 0);
    acc[1][0] = __builtin_amdgcn_mfma_f32_16x16x32_bf16(a1, b0, acc[1][0], 0, 0, 0);
    acc[1][1] = __builtin_amdgcn_mfma_f32_16x16x32_bf16(a1, b1, acc[1][1], 0, 0, 0);
    __syncthreads();
  }

#pragma unroll
  for (int mr = 0; mr < 2; ++mr)
#pragma unroll
    for (int nr = 0; nr < 2; ++nr)
#pragma unroll
      for (int r = 0; r < 4; ++r) {
        int row = bm + wr * 32 + mr * 16 + g * 4 + r;
        int col = bn + wc * 32 + nr * 16 + li;
        if (row >= M) continue;
        float v = acc[mr][nr][r] + bias[col];
        if (EPI == 1) v = gelu_exact(v);
        if (EPI == 2) {
          v += resid[(long)row * N + col];
          v = mask[row] ? v : 0.f;
          ((float*)Cv)[(long)row * N + col] = v;
        } else {
          ((u16*)Cv)[(long)row * N + col] = f2bs(v);
        }
      }
}

// ---------------------------------------------------------------------------
// Fused K+V projection GEMM: A = kv_ln [8192x256], BT = [WkT; WvT] (512x256).
// bn < 256 -> Kh[b][h][key][dchunk ^ ((key>>1)&3)]   (swizzled 16B chunks)
// bn >= 256 -> Vh[b][h][key/32][d][kchunk ^ ((d>>1)&6)] (swizzled 8B chunks)
// ---------------------------------------------------------------------------
__global__ __launch_bounds__(256) void gemm_kv(
    const u16* __restrict__ A, const u16* __restrict__ BT,
    const float* __restrict__ biasK, const float* __restrict__ biasV,
    u16* __restrict__ Kh, u16* __restrict__ Vh) {
  __shared__ short As[64][40];
  __shared__ short Bs[64][40];
  int bm = blockIdx.y * 64, bn = blockIdx.x * 64;
  int tid = threadIdx.x;
  int lane = tid & 63, w = tid >> 6;
  int g = lane >> 4, li = lane & 15;
  int wr = w >> 1, wc = w & 1;
  f32x4 acc[2][2] = {};

  int srow = tid >> 2, skc = (tid & 3) * 8;
  for (int k0 = 0; k0 < D; k0 += 32) {
    {
      bf16x8 av = *reinterpret_cast<const bf16x8*>(
          A + (long)(bm + srow) * D + k0 + skc);
      *reinterpret_cast<bf16x8*>(&As[srow][skc]) = av;
      bf16x8 bv = *reinterpret_cast<const bf16x8*>(
          BT + (long)(bn + srow) * D + k0 + skc);
      *reinterpret_cast<bf16x8*>(&Bs[srow][skc]) = bv;
    }
    __syncthreads();
    bf16x8 a0 = *reinterpret_cast<const bf16x8*>(&As[wr * 32 + li][g * 8]);
    bf16x8 a1 = *reinterpret_cast<const bf16x8*>(&As[wr * 32 + 16 + li][g * 8]);
    bf16x8 b0 = *reinterpret_cast<const bf16x8*>(&Bs[wc * 32 + li][g * 8]);
    bf16x8 b1 = *reinterpret_cast<const bf16x8*>(&Bs[wc * 32 + 16 + li][g * 8]);
    acc[0][0] = __builtin_amdgcn_mfma_f32_16x16x32_bf16(a0, b0, acc[0][0], 0, 0, 0);
    acc[0][1] = __builtin_amdgcn_mfma_f32_16x16x32_bf16(a0, b1, acc[0][1], 0, 0, 0);
    acc[1][0] = __builtin_amdgcn_mfma_f32_16x16x32_bf16(a1, b0, acc[1][0], 0, 0, 0);
    acc[1][1] = __builtin_amdgcn_mfma_f32_16x16x32_bf16(a1, b1, acc[1][1], 0, 0, 0);
    __syncthreads();
  }

  if (bn < 256) {
    __shared__ u16 Ct[64][72];
#pragma unroll
    for (int mr = 0; mr < 2; ++mr)
#pragma unroll
      for (int nr = 0; nr < 2; ++nr)
#pragma unroll
        for (int r = 0; r < 4; ++r) {
          int rowL = wr * 32 + mr * 16 + g * 4 + r;
          int colL = wc * 32 + nr * 16 + li;
          Ct[rowL][colL] = f2bs(acc[mr][nr][r] + biasK[bn + colL]);
        }
    __syncthreads();
#pragma unroll
    for (int p = 0; p < 2; ++p) {
      int rowL = (tid >> 3) + p * 32;
      int c8 = (tid & 7) * 8;
      int grow = bm + rowL;
      int b2 = grow >> 12, key = grow & (L - 1);
      int gcol = bn + c8;
      int hh = gcol >> 5, dd = gcol & (HD - 1);
      int cst = (dd >> 3) ^ ((key >> 1) & 3);  // swizzled 16B chunk slot
      u16* dst = Kh + (((long)(b2 * H + hh) * L + key) * 32 + (cst << 3));
      *reinterpret_cast<bf16x8*>(dst) =
          *reinterpret_cast<const bf16x8*>(&Ct[rowL][c8]);
    }
  } else {
    int vbn = bn - 256;
    __shared__ u16 Ct[64][72];
#pragma unroll
    for (int mr = 0; mr < 2; ++mr)
#pragma unroll
      for (int nr = 0; nr < 2; ++nr)
#pragma unroll
        for (int r = 0; r < 4; ++r) {
          int rowL = wr * 32 + mr * 16 + g * 4 + r;
          int colL = wc * 32 + nr * 16 + li;
          Ct[colL][rowL] = f2bs(acc[mr][nr][r] + biasV[vbn + colL]);
        }
    __syncthreads();
    int b2 = bm >> 12;
#pragma unroll
    for (int p = 0; p < 2; ++p) {
      int colL = (tid >> 3) + p * 32;
      int rem = tid & 7;
      int kb = rem >> 2, k8 = (rem & 3) * 8;
      int gcol = vbn + colL;
      int hh = gcol >> 5, dd = gcol & (HD - 1);
      int kb32 = ((bm & (L - 1)) >> 5) + kb;
      int j = (k8 >> 2) ^ ((dd >> 1) & 6);  // swizzled 8B-chunk pair slot
      u16* dst = Vh + (((long)(b2 * H + hh) * (L / 32) + kb32) * 1024 +
                       dd * 32 + (j << 2));
      *reinterpret_cast<bf16x8*>(dst) =
          *reinterpret_cast<const bf16x8*>(&Ct[colL][kb * 32 + k8]);
    }
  }
}

// ---------------------------------------------------------------------------
// Fused flash attention: 512 threads = 8 split-K waves per (b,h,32-q tile).
// SINGLE 4KB wave-private LDS buffer via global_load_lds DMA; per-iteration
// issue -> vmcnt(0) -> compute, latency hidden by TLP (34KB LDS -> up to
// 4 blocks/CU = 32 waves/CU). Kh/Vh XOR-swizzled in global (conflict-free
// reads). No-max exp2 softmax -> plain-sum split-K combine. XCD swizzle.
// ---------------------------------------------------------------------------
constexpr int POOLSZ = NSPLIT * 32 * 33 * 4 + NSPLIT * 32 * 4;  // 34816

__global__ __launch_bounds__(512) void attn_mfma(
    const u16* __restrict__ Qb, const u16* __restrict__ Kh,
    const u16* __restrict__ Vh, u16* __restrict__ AO) {
  __shared__ alignas(16) char pool[POOLSZ];
  int i = blockIdx.x;
  int xcd = i & 7, slot = i >> 3;          // 66 slots per XCD
  int bh = (xcd << 1) | (slot >= NQT ? 1 : 0);
  int qt = (slot >= NQT) ? slot - NQT : slot;
  int h = bh & 7;
  int b = bh >> 3;
  int tid = threadIdx.x, w = tid >> 6, lane = tid & 63;
  int g = lane >> 4, li = lane & 15;

  fr qf0, qf1;
  {
    const float QSC = 0.25509836048f;  // (1/sqrt(32)) * log2(e)
#pragma unroll
    for (int qb = 0; qb < 2; ++qb) {
      int qrow = qt * 32 + qb * 16 + li;
      if (qrow >= Q_MAX) qrow = Q_MAX - 1;
      bf16x8 raw = *reinterpret_cast<const bf16x8*>(
          Qb + ((long)(b * Q_MAX + qrow)) * D + h * HD + g * 8);
      fr& qf = qb ? qf1 : qf0;
#pragma unroll
      for (int j = 0; j < 4; ++j)
        qf.i[j] = (int)cvt_pk(bs2f((u16)raw[2 * j]) * QSC,
                              bs2f((u16)raw[2 * j + 1]) * QSC);
    }
  }

  f32x4 acc00 = {}, acc01 = {}, acc10 = {}, acc11 = {};
  float den0 = 0.f, den1 = 0.f;
  const f32x4 z = {};

  const u16* kbase = Kh + ((long)(b * H + h) * L) * HD;
  const u16* vbase = Vh + ((long)(b * H + h) * L) * HD;
  int kstart = w * KCHUNK;
  char* wbase = pool + w * 4096;  // wave-private single buffer (2KB K + 2KB V)

  // swizzled LDS read offsets (u16 units)
  int s_li = (li >> 1) & 3;
  int t_li = (li >> 1) & 6;
  int kof0 = li * 32 + ((g ^ s_li) << 3);
  int kof1 = (16 + li) * 32 + ((g ^ s_li) << 3);
  int va0o = li * 32 + ((g ^ t_li) << 2);
  int vb0o = li * 32 + (((4 + g) ^ t_li) << 2);
  int va1o = (16 + li) * 32 + ((g ^ t_li) << 2);
  int vb1o = (16 + li) * 32 + (((4 + g) ^ t_li) << 2);

  for (int t = 0; t < NT; ++t) {
    {
      const u16* ks = kbase + (long)(kstart + t * 32) * HD + lane * 8;
      const u16* vs = vbase + (long)(kstart + t * 32) * HD + lane * 8;
      u16* lk = (u16*)wbase;
      // prior iter's LDS reads must complete before DMA overwrites buffer
      asm volatile("s_waitcnt lgkmcnt(0)" ::: "memory");
      GLL16(ks, lk);
      GLL16(ks + 512, lk + 512);
      GLL16(vs, lk + 1024);
      GLL16(vs + 512, lk + 1536);
      asm volatile("s_waitcnt vmcnt(0)" ::: "memory");
      __builtin_amdgcn_sched_barrier(0);
    }

    const u16* kl = (const u16*)wbase;
    const u16* vl = kl + 1024;
    bf16x8 kf0 = *reinterpret_cast<const bf16x8*>(kl + kof0);
    bf16x8 kf1 = *reinterpret_cast<const bf16x8*>(kl + kof1);
    uint2 va0 = *reinterpret_cast<const uint2*>(vl + va0o);
    uint2 vb0 = *reinterpret_cast<const uint2*>(vl + vb0o);
    uint2 va1 = *reinterpret_cast<const uint2*>(vl + va1o);
    uint2 vb1 = *reinterpret_cast<const uint2*>(vl + vb1o);

    f32x4 s00 = __builtin_amdgcn_mfma_f32_16x16x32_bf16(kf0, qf0.h, z, 0, 0, 0);
    f32x4 s10 = __builtin_amdgcn_mfma_f32_16x16x32_bf16(kf1, qf0.h, z, 0, 0, 0);
    f32x4 s01 = __builtin_amdgcn_mfma_f32_16x16x32_bf16(kf0, qf1.h, z, 0, 0, 0);
    f32x4 s11 = __builtin_amdgcn_mfma_f32_16x16x32_bf16(kf1, qf1.h, z, 0, 0, 0);

    float p00[4], p10[4], p01[4], p11[4];
#pragma unroll
    for (int r = 0; r < 4; ++r) {
      p00[r] = exp2f(s00[r]);
      p10[r] = exp2f(s10[r]);
      p01[r] = exp2f(s01[r]);
      p11[r] = exp2f(s11[r]);
      den0 += p00[r] + p10[r];
      den1 += p01[r] + p11[r];
    }
    fr pf0, pf1;
    pf0.i[0] = (int)cvt_pk(p00[0], p00[1]);
    pf0.i[1] = (int)cvt_pk(p00[2], p00[3]);
    pf0.i[2] = (int)cvt_pk(p10[0], p10[1]);
    pf0.i[3] = (int)cvt_pk(p10[2], p10[3]);
    pf1.i[0] = (int)cvt_pk(p01[0], p01[1]);
    pf1.i[1] = (int)cvt_pk(p01[2], p01[3]);
    pf1.i[2] = (int)cvt_pk(p11[0], p11[1]);
    pf1.i[3] = (int)cvt_pk(p11[2], p11[3]);

    fr v0, v1;
    v0.i = (i32x4){(int)va0.x, (int)va0.y, (int)vb0.x, (int)vb0.y};
    v1.i = (i32x4){(int)va1.x, (int)va1.y, (int)vb1.x, (int)vb1.y};
    acc00 = __builtin_amdgcn_mfma_f32_16x16x32_bf16(v0.h, pf0.h, acc00, 0, 0, 0);
    acc01 = __builtin_amdgcn_mfma_f32_16x16x32_bf16(v0.h, pf1.h, acc01, 0, 0, 0);
    acc10 = __builtin_amdgcn_mfma_f32_16x16x32_bf16(v1.h, pf0.h, acc10, 0, 0, 0);
    acc11 = __builtin_amdgcn_mfma_f32_16x16x32_bf16(v1.h, pf1.h, acc11, 0, 0, 0);
  }

  // reduce per-lane denominators over g
  den0 += __shfl_xor(den0, 16, 64);
  den0 += __shfl_xor(den0, 32, 64);
  den1 += __shfl_xor(den1, 16, 64);
  den1 += __shfl_xor(den1, 32, 64);

  // combine: overlay staging LDS (all waves done with it after barrier)
  __syncthreads();
  float (*accs)[32][33] = (float(*)[32][33])pool;
  float (*dsh)[32] = (float(*)[32])(pool + NSPLIT * 32 * 33 * 4);
#pragma unroll
  for (int r = 0; r < 4; ++r) {
    accs[w][g * 4 + r][li] = acc00[r];
    accs[w][g * 4 + r][16 + li] = acc01[r];
    accs[w][16 + g * 4 + r][li] = acc10[r];
    accs[w][16 + g * 4 + r][16 + li] = acc11[r];
  }
  if (g == 0) {
    dsh[w][li] = den0;
    dsh[w][16 + li] = den1;
  }
  __syncthreads();

  int q = tid >> 4, dp = tid & 15;  // q 0..31, d-pair 0..15
  float Den = 0.f, o0 = 0.f, o1 = 0.f;
#pragma unroll
  for (int ww = 0; ww < NSPLIT; ++ww) {
    Den += dsh[ww][q];
    o0 += accs[ww][2 * dp][q];
    o1 += accs[ww][2 * dp + 1][q];
  }
  float inv = 1.f / Den;
  int qrow = qt * 32 + q;
  if (qrow < Q_MAX) {
    unsigned pk = cvt_pk(o0 * inv, o1 * inv);
    *reinterpret_cast<unsigned*>(
        AO + ((long)(b * Q_MAX + qrow)) * D + h * HD + 2 * dp) = pk;
  }
}

// ---------------------------------------------------------------------------
__global__ __launch_bounds__(256) void head_kernel(
    const float* __restrict__ enc, const float* __restrict__ hW,
    const float* __restrict__ hb, float* __restrict__ out) {
  int row = blockIdx.x * 4 + (threadIdx.x >> 6);
  int lane = threadIdx.x & 63;
  const float4 a = *reinterpret_cast<const float4*>(enc + (long)row * D + lane * 4);
  float c0 = 0.f, c1 = 0.f, c2 = 0.f;
  const float av[4] = {a.x, a.y, a.z, a.w};
#pragma unroll
  for (int i = 0; i < 4; ++i) {
    int k = lane * 4 + i;
    c0 += av[i] * hW[k * 3];
    c1 += av[i] * hW[k * 3 + 1];
    c2 += av[i] * hW[k * 3 + 2];
  }
#pragma unroll
  for (int off = 32; off; off >>= 1) {
    c0 += __shfl_down(c0, off, 64);
    c1 += __shfl_down(c1, off, 64);
    c2 += __shfl_down(c2, off, 64);
  }
  if (lane == 0) {
    out[(long)row * 3] = c0 + hb[0];
    out[(long)row * 3 + 1] = c1 + hb[1];
    out[(long)row * 3 + 2] = c2 + hb[2];
  }
}

// ---------------------------------------------------------------------------
__global__ __launch_bounds__(64) void overwrite_kernel(
    const float* __restrict__ q_stream, const int* __restrict__ idx,
    const int* __restrict__ mask, const float* __restrict__ hW,
    const float* __restrict__ hb, float* __restrict__ out) {
  int j = blockIdx.x;
  if (!mask[j]) return;
  int b = j / Q_MAX;
  int p = idx[j];
  int lane = threadIdx.x;
  const float* a = q_stream + (long)j * D;
  float a0 = a[lane], a1 = a[lane + 64], a2 = a[lane + 128],
        a3 = a[lane + 192];
  for (int c = 0; c < 3; ++c) {
    float s = a0 * hW[lane * 3 + c] + a1 * hW[(lane + 64) * 3 + c] +
              a2 * hW[(lane + 128) * 3 + c] + a3 * hW[(lane + 192) * 3 + c];
    for (int off = 32; off > 0; off >>= 1) s += __shfl_down(s, off, 64);
    if (lane == 0) out[((long)b * L + p) * 3 + c] = s + hb[c];
  }
}

// ---------------------------------------------------------------------------
extern "C" void kernel_launch(void* const* d_in, const int* in_sizes, int n_in,
                              void* d_out, int out_size, void* d_ws,
                              size_t ws_size, hipStream_t stream) {
  const float* enc = (const float*)d_in[0];
  const float* clog = (const float*)d_in[1];
  const float* ln_q_g = (const float*)d_in[2];
  const float* ln_q_b = (const float*)d_in[3];
  const float* ln_kv_g = (const float*)d_in[4];
  const float* ln_kv_b = (const float*)d_in[5];
  const float* Wq = (const float*)d_in[6];
  const float* bq = (const float*)d_in[7];
  const float* Wk = (const float*)d_in[8];
  const float* bk = (const float*)d_in[9];
  const float* Wv = (const float*)d_in[10];
  const float* bv = (const float*)d_in[11];
  const float* Wo = (const float*)d_in[12];
  const float* bo = (const float*)d_in[13];
  const float* ffn_g = (const float*)d_in[14];
  const float* ffn_b = (const float*)d_in[15];
  const float* W1 = (const float*)d_in[16];
  const float* b1 = (const float*)d_in[17];
  const float* W2 = (const float*)d_in[18];
  const float* b2 = (const float*)d_in[19];
  const float* head_W = (const float*)d_in[20];
  const float* head_b = (const float*)d_in[21];
  float* out = (float*)d_out;

  char* ws = (char*)d_ws;
  float* q_stream = (float*)ws;            ws += (long)QROWS * D * 4;
  u16* kvl0 = (u16*)ws;                    ws += (long)KVROWS * D * 2;
  u16* kvl1 = (u16*)ws;                    ws += (long)KVROWS * D * 2;
  u16* Khbuf = (u16*)ws;                   ws += (long)B * H * L * HD * 2;
  u16* Vhbuf = (u16*)ws;                   ws += (long)B * H * L * HD * 2;
  u16* q_ln = (u16*)ws;                    ws += (long)QROWS * D * 2;
  u16* Qbuf = (u16*)ws;                    ws += (long)QROWS * D * 2;
  u16* AObuf = (u16*)ws;                   ws += (long)QROWS * D * 2;
  u16* H1buf = (u16*)ws;                   ws += (long)QROWS * FF * 2;
  u16* WT = (u16*)ws;                      ws += (long)NL * (4 * D * D + 2 * D * FF) * 2;
  int* idxbuf = (int*)ws;                  ws += QROWS * 4;
  int* maskbuf = (int*)ws;

  const long DD = (long)D * D, DFF = (long)D * FF;
  const long LSTR = 4 * DD + 2 * DFF;

  transpose_tiled<<<NL * 192, 256, 0, stream>>>(Wq, Wk, Wv, Wo, W1, W2, WT);
  ln_kv2<<<KVROWS, 256, 0, stream>>>(enc, kvl0, kvl1, ln_kv_g, ln_kv_b);
  select_kernel<<<B, 1024, 0, stream>>>(clog, idxbuf, maskbuf);
  gather_kernel<<<QROWS, 256, 0, stream>>>(enc, idxbuf, q_stream);

  for (int l = 0; l < NL; ++l) {
    u16* base = WT + l * LSTR;
    u16* kv_ln = (l == 0) ? kvl0 : kvl1;

    ln_bf16<<<QROWS, 256, 0, stream>>>(q_stream, q_ln, ln_q_g + l * D, ln_q_b + l * D);

    dim3 gKV(512 / 64, KVROWS / 64);
    gemm_kv<<<gKV, 256, 0, stream>>>(kv_ln, base, bk + l * D, bv + l * D,
                                     Khbuf, Vhbuf);
    dim3 gQ(D / 64, (QROWS + 63) / 64);
    gemm_mfma<0><<<gQ, 256, 0, stream>>>(q_ln, base + 2 * DD, bq + l * D,
                                         (void*)Qbuf, nullptr, nullptr,
                                         QROWS, D, D);

    attn_mfma<<<B * H * NQT, 512, 0, stream>>>(Qbuf, Khbuf, Vhbuf, AObuf);

    gemm_mfma<2><<<gQ, 256, 0, stream>>>(AObuf, base + 3 * DD, bo + l * D,
                                         (void*)q_stream, q_stream, maskbuf,
                                         QROWS, D, D);

    ln_bf16<<<QROWS, 256, 0, stream>>>(q_stream, q_ln, ffn_g + l * D, ffn_b + l * D);
    dim3 gF1(FF / 64, (QROWS + 63) / 64);
    gemm_mfma<1><<<gF1, 256, 0, stream>>>(q_ln, base + 4 * DD, b1 + l * FF,
                                          (void*)H1buf, nullptr, nullptr,
                                          QROWS, FF, D);
    dim3 gF2(D / 64, (QROWS + 63) / 64);
    gemm_mfma<2><<<gF2, 256, 0, stream>>>(H1buf, base + 4 * DD + DFF,
                                          b2 + l * D, (void*)q_stream,
                                          q_stream, maskbuf, QROWS, D, FF);
  }

  head_kernel<<<KVROWS / 4, 256, 0, stream>>>(enc, head_W, head_b, out);
  overwrite_kernel<<<QROWS, 64, 0, stream>>>(q_stream, idxbuf, maskbuf, head_W,
                                             head_b, out);
}

// Round 12
// 230.534 us; speedup vs baseline: 1.4957x; 1.0454x over previous
//
#include <hip/hip_runtime.h>
#include <cmath>

constexpr int B = 2, L = 4096, D = 256, H = 8, NC = 3;
constexpr int TOP_N = 8, R = 32;
constexpr int LS = 1000, LE = 3000;
constexpr int NL = 2;
constexpr int FF = 4 * D;                        // 1024
constexpr int Q_MAX = 2 * TOP_N * (2 * R + 1);   // 1040
constexpr int HD = D / H;                        // 32
constexpr int QROWS = B * Q_MAX;                 // 2080
constexpr int KVROWS = B * L;                    // 8192
constexpr int NQT = (Q_MAX + 31) / 32;           // 33 q-tiles of 32
constexpr int NREG = LE - LS;                    // 2000
constexpr int NSPLIT = 8;                        // split-K waves per block
constexpr int KCHUNK = L / NSPLIT;               // 512 keys per wave
constexpr int NT = KCHUNK / 32;                  // 16 iterations
constexpr int KVBLK = 8 * (KVROWS / 64);         // 1024 blocks (KV part)
constexpr int QBLK = 4 * ((QROWS + 63) / 64);    // 132 blocks (Q part)

typedef __attribute__((ext_vector_type(8))) short bf16x8;
typedef __attribute__((ext_vector_type(4))) float f32x4;
typedef __attribute__((ext_vector_type(4))) int i32x4;
typedef unsigned short u16;

union fr {
  bf16x8 h;
  i32x4 i;
};

__device__ __forceinline__ u16 f2bs(float f) {
  unsigned int u = __float_as_uint(f);
  unsigned int r = u + 0x7fffu + ((u >> 16) & 1u);
  return (u16)(r >> 16);
}
__device__ __forceinline__ float bs2f(u16 s) {
  return __uint_as_float(((unsigned int)s) << 16);
}
__device__ __forceinline__ float gelu_exact(float x) {
  return 0.5f * x * (1.f + erff(x * 0.70710678118654752440f));
}
__device__ __forceinline__ unsigned cvt_pk(float lo, float hi) {
  unsigned r;
  asm("v_cvt_pk_bf16_f32 %0, %1, %2" : "=v"(r) : "v"(lo), "v"(hi));
  return r;
}

#define GLL16(gsrc, ldst)                                                   \
  __builtin_amdgcn_global_load_lds(                                         \
      (const __attribute__((address_space(1))) unsigned int*)(gsrc),        \
      (__attribute__((address_space(3))) unsigned int*)(ldst), 16, 0, 0)

// ---------------------------------------------------------------------------
// Vicinity selection, wave-parallel top-8. One 1024-thread block per batch.
// Per channel: 16 waves each hold 2 candidate values in regs and extract
// their local top-8 via in-register wave-argmax (no barriers); wave 0 then
// reduces the 128 candidates. Dedup via bitmap + prefix scan (set of unique
// positions is order-invariant for the final output).
// ---------------------------------------------------------------------------
__global__ __launch_bounds__(1024) void select_kernel(
    const float* __restrict__ logits, int* __restrict__ idx_out,
    int* __restrict__ mask_out) {
  int b = blockIdx.x;
  int tid = threadIdx.x;
  int w = tid >> 6, lane = tid & 63;
  __shared__ float candv[16][8];
  __shared__ int candi[16][8];
  __shared__ int centers[2 * TOP_N];
  __shared__ unsigned present[L / 32];
  __shared__ int offs[128];
  __shared__ int wtot[2];

  // per-thread values for both channels (2 positions each)
  float vd[2], va[2];
  int pidx[2];
#pragma unroll
  for (int j = 0; j < 2; ++j) {
    int p = tid + j * 1024;
    pidx[j] = p;
    if (p < NREG) {
      const float* lg = logits + ((long)b * L + LS + p) * NC;
      float x0 = lg[0], x1 = lg[1], x2 = lg[2];
      float m = fmaxf(x0, fmaxf(x1, x2));
      float lse = m + logf(expf(x0 - m) + expf(x1 - m) + expf(x2 - m));
      vd[j] = x2 - lse;  // don
      va[j] = x1 - lse;  // acc
    } else {
      vd[j] = -INFINITY;
      va[j] = -INFINITY;
    }
  }
  if (tid < 128) present[tid] = 0;

  for (int sel = 0; sel < 2; ++sel) {
    float v0 = (sel == 0) ? vd[0] : va[0];
    float v1 = (sel == 0) ? vd[1] : va[1];
    // stage 1: each wave extracts its local top-8 (register-only)
#pragma unroll
    for (int r = 0; r < TOP_N; ++r) {
      float mv;
      int mi;
      if (v0 >= v1) { mv = v0; mi = pidx[0]; }
      else { mv = v1; mi = pidx[1]; }
#pragma unroll
      for (int off = 32; off; off >>= 1) {
        float ov = __shfl_xor(mv, off, 64);
        int oi = __shfl_xor(mi, off, 64);
        if (ov > mv || (ov == mv && oi < mi)) { mv = ov; mi = oi; }
      }
      if (pidx[0] == mi) v0 = -INFINITY;
      if (pidx[1] == mi) v1 = -INFINITY;
      if (lane == 0) { candv[w][r] = mv; candi[w][r] = mi; }
    }
    __syncthreads();
    // stage 2: wave 0 reduces the 128 candidates to global top-8
    if (tid < 64) {
      int j0 = tid, j1 = tid + 64;
      float c0 = candv[j0 >> 3][j0 & 7], c1 = candv[j1 >> 3][j1 & 7];
      int i0 = candi[j0 >> 3][j0 & 7], i1 = candi[j1 >> 3][j1 & 7];
#pragma unroll
      for (int r = 0; r < TOP_N; ++r) {
        float mv;
        int mi;
        if (c0 > c1 || (c0 == c1 && i0 < i1)) { mv = c0; mi = i0; }
        else { mv = c1; mi = i1; }
#pragma unroll
        for (int off = 32; off; off >>= 1) {
          float ov = __shfl_xor(mv, off, 64);
          int oi = __shfl_xor(mi, off, 64);
          if (ov > mv || (ov == mv && oi < mi)) { mv = ov; mi = oi; }
        }
        if (i0 == mi) c0 = -INFINITY;
        if (i1 == mi) c1 = -INFINITY;
        if (tid == 0) centers[sel * TOP_N + r] = LS + mi;
      }
    }
    __syncthreads();
  }

  for (int j = tid; j < Q_MAX; j += 1024) {
    int c = centers[j / (2 * R + 1)];
    int off = j % (2 * R + 1) - R;
    int v = c + off;
    v = v < 0 ? 0 : (v > L - 1 ? L - 1 : v);
    atomicOr(&present[v >> 5], 1u << (v & 31));
  }
  __syncthreads();

  int cnt = (tid < 128) ? __popc(present[tid]) : 0;
  if (tid < 128) {
    int x = cnt;
#pragma unroll
    for (int off = 1; off < 64; off <<= 1) {
      int o = __shfl_up(x, off, 64);
      if ((tid & 63) >= off) x += o;
    }
    if ((tid & 63) == 63) wtot[tid >> 6] = x;
    offs[tid] = x - cnt;
  }
  __syncthreads();
  int total = wtot[0] + wtot[1];
  if (tid < 128) {
    int base = offs[tid] + ((tid >= 64) ? wtot[0] : 0);
    unsigned mword = present[tid];
    while (mword) {
      int i = __ffs(mword) - 1;
      mword &= mword - 1;
      idx_out[b * Q_MAX + base] = tid * 32 + i;
      mask_out[b * Q_MAX + base] = 1;
      ++base;
    }
  }
  for (int j = total + tid; j < Q_MAX; j += 1024) {
    idx_out[b * Q_MAX + j] = L;
    mask_out[b * Q_MAX + j] = 0;
  }
}

// ---------------------------------------------------------------------------
__global__ __launch_bounds__(256) void gather_kernel(
    const float* __restrict__ enc, const int* __restrict__ idx,
    float* __restrict__ q_stream) {
  int row = blockIdx.x;
  int b = row / Q_MAX;
  int p = idx[row];
  float v = 0.f;
  if (p < L) v = enc[((long)b * L + p) * D + threadIdx.x];
  q_stream[(long)row * D + threadIdx.x] = v;
}

// ---------------------------------------------------------------------------
__global__ __launch_bounds__(256) void ln_bf16(
    const float* __restrict__ in, u16* __restrict__ out,
    const float* __restrict__ gg, const float* __restrict__ bb) {
  long row = blockIdx.x;
  int tid = threadIdx.x;
  float x = in[row * D + tid];
  float s1 = x, s2 = x * x;
#pragma unroll
  for (int off = 32; off; off >>= 1) {
    s1 += __shfl_xor(s1, off, 64);
    s2 += __shfl_xor(s2, off, 64);
  }
  __shared__ float p1[4], p2[4];
  int w = tid >> 6;
  if ((tid & 63) == 0) { p1[w] = s1; p2[w] = s2; }
  __syncthreads();
  s1 = p1[0] + p1[1] + p1[2] + p1[3];
  s2 = p2[0] + p2[1] + p2[2] + p2[3];
  float mean = s1 * (1.f / D);
  float var = fmaxf(s2 * (1.f / D) - mean * mean, 0.f);
  float r = rsqrtf(var + 1e-5f);
  out[row * D + tid] = f2bs((x - mean) * r * gg[tid] + bb[tid]);
}

// LayerNorm of enc with BOTH layers' gamma/beta -> two bf16 outputs
__global__ __launch_bounds__(256) void ln_kv2(
    const float* __restrict__ in, u16* __restrict__ o0, u16* __restrict__ o1,
    const float* __restrict__ gg, const float* __restrict__ bb) {
  long row = blockIdx.x;
  int tid = threadIdx.x;
  float x = in[row * D + tid];
  float s1 = x, s2 = x * x;
#pragma unroll
  for (int off = 32; off; off >>= 1) {
    s1 += __shfl_xor(s1, off, 64);
    s2 += __shfl_xor(s2, off, 64);
  }
  __shared__ float p1[4], p2[4];
  int w = tid >> 6;
  if ((tid & 63) == 0) { p1[w] = s1; p2[w] = s2; }
  __syncthreads();
  s1 = p1[0] + p1[1] + p1[2] + p1[3];
  s2 = p2[0] + p2[1] + p2[2] + p2[3];
  float mean = s1 * (1.f / D);
  float var = fmaxf(s2 * (1.f / D) - mean * mean, 0.f);
  float r = rsqrtf(var + 1e-5f);
  float xn = (x - mean) * r;
  o0[row * D + tid] = f2bs(xn * gg[tid] + bb[tid]);
  o1[row * D + tid] = f2bs(xn * gg[D + tid] + bb[D + tid]);
}

// ---------------------------------------------------------------------------
// LDS-tiled weight transpose+bf16 (coalesced reads AND writes).
// ---------------------------------------------------------------------------
__global__ __launch_bounds__(256) void transpose_tiled(
    const float* __restrict__ Wq_, const float* __restrict__ Wk_,
    const float* __restrict__ Wv_, const float* __restrict__ Wo_,
    const float* __restrict__ W1_, const float* __restrict__ W2_,
    u16* __restrict__ WT) {
  __shared__ u16 T[64][65];
  const long DD = (long)D * D, DFF = (long)D * FF;
  const long LSTR = 4 * DD + 2 * DFF;
  int t = blockIdx.x;
  int l = t / 192, r = t % 192;
  const float* src;
  long dbase;
  int K_, N_, kt, nt;
  if (r < 64) {
    int which = r >> 4, sub = r & 15;
    kt = sub >> 2;
    nt = sub & 3;
    K_ = 256;
    N_ = 256;
    src = (which == 0 ? Wk_ : which == 1 ? Wv_ : which == 2 ? Wq_ : Wo_) +
          (long)l * DD;
    dbase = (long)l * LSTR + (long)which * DD;
  } else if (r < 128) {
    int sub = r - 64;
    kt = sub >> 4;
    nt = sub & 15;
    K_ = 256;
    N_ = 1024;
    src = W1_ + (long)l * DFF;
    dbase = (long)l * LSTR + 4 * DD;
  } else {
    int sub = r - 128;
    kt = sub >> 2;
    nt = sub & 3;
    K_ = 1024;
    N_ = 256;
    src = W2_ + (long)l * DFF;
    dbase = (long)l * LSTR + 4 * DD + DFF;
  }
  int k0 = kt * 64, n0 = nt * 64;
  {
    int kr = threadIdx.x >> 2, c16 = (threadIdx.x & 3) * 16;
    const float* sp = src + (long)(k0 + kr) * N_ + n0 + c16;
#pragma unroll
    for (int i = 0; i < 4; ++i) {
      float4 v = *reinterpret_cast<const float4*>(sp + 4 * i);
      T[kr][c16 + 4 * i + 0] = f2bs(v.x);
      T[kr][c16 + 4 * i + 1] = f2bs(v.y);
      T[kr][c16 + 4 * i + 2] = f2bs(v.z);
      T[kr][c16 + 4 * i + 3] = f2bs(v.w);
    }
  }
  __syncthreads();
  {
    int nr = threadIdx.x >> 2, kc = (threadIdx.x & 3) * 16;
    u16 tmp[16];
#pragma unroll
    for (int j = 0; j < 16; ++j) tmp[j] = T[kc + j][nr];
    u16* dp = WT + dbase + (long)(n0 + nr) * K_ + k0 + kc;
    *reinterpret_cast<bf16x8*>(dp) = *reinterpret_cast<const bf16x8*>(&tmp[0]);
    *reinterpret_cast<bf16x8*>(dp + 8) =
        *reinterpret_cast<const bf16x8*>(&tmp[8]);
  }
}

// ---------------------------------------------------------------------------
// bf16 MFMA GEMM (64x64 tile, BK=32, 4 waves).
// EPI 1: gelu->bf16; 2: resid+mask->f32
// ---------------------------------------------------------------------------
template <int EPI>
__global__ __launch_bounds__(256) void gemm_mfma(
    const u16* __restrict__ A, const u16* __restrict__ BT,
    const float* __restrict__ bias, void* __restrict__ Cv,
    const float* __restrict__ resid, const int* __restrict__ mask, int M,
    int N, int K) {
  __shared__ short As[64][40];
  __shared__ short Bs[64][40];
  int bm = blockIdx.y * 64, bn = blockIdx.x * 64;
  int tid = threadIdx.x;
  int lane = tid & 63, w = tid >> 6;
  int g = lane >> 4, li = lane & 15;
  int wr = w >> 1, wc = w & 1;
  f32x4 acc[2][2] = {};

  int srow = tid >> 2, skc = (tid & 3) * 8;
  for (int k0 = 0; k0 < K; k0 += 32) {
    {
      int grow = bm + srow;
      bf16x8 av = {};
      if (grow < M)
        av = *reinterpret_cast<const bf16x8*>(A + (long)grow * K + k0 + skc);
      *reinterpret_cast<bf16x8*>(&As[srow][skc]) = av;
      bf16x8 bv = *reinterpret_cast<const bf16x8*>(
          BT + (long)(bn + srow) * K + k0 + skc);
      *reinterpret_cast<bf16x8*>(&Bs[srow][skc]) = bv;
    }
    __syncthreads();
    bf16x8 a0 = *reinterpret_cast<const bf16x8*>(&As[wr * 32 + li][g * 8]);
    bf16x8 a1 = *reinterpret_cast<const bf16x8*>(&As[wr * 32 + 16 + li][g * 8]);
    bf16x8 b0 = *reinterpret_cast<const bf16x8*>(&Bs[wc * 32 + li][g * 8]);
    bf16x8 b1 = *reinterpret_cast<const bf16x8*>(&Bs[wc * 32 + 16 + li][g * 8]);
    acc[0][0] = __builtin_amdgcn_mfma_f32_16x16x32_bf16(a0, b0, acc[0][0], 0, 0, 0);
    acc[0][1] = __builtin_amdgcn_mfma_f32_16x16x32_bf16(a0, b1, acc[0][1], 0, 0, 0);
    acc[1][0] = __builtin_amdgcn_mfma_f32_16x16x32_bf16(a1, b0, acc[1][0], 0, 0, 0);
    acc[1][1] = __builtin_amdgcn_mfma_f32_16x16x32_bf16(a1, b1, acc[1][1], 0, 0, 0);
    __syncthreads();
  }

#pragma unroll
  for (int mr = 0; mr < 2; ++mr)
#pragma unroll
    for (int nr = 0; nr < 2; ++nr)
#pragma unroll
      for (int r = 0; r < 4; ++r) {
        int row = bm + wr * 32 + mr * 16 + g * 4 + r;
        int col = bn + wc * 32 + nr * 16 + li;
        if (row >= M) continue;
        float v = acc[mr][nr][r] + bias[col];
        if (EPI == 1) v = gelu_exact(v);
        if (EPI == 2) {
          v += resid[(long)row * N + col];
          v = mask[row] ? v : 0.f;
          ((float*)Cv)[(long)row * N + col] = v;
        } else {
          ((u16*)Cv)[(long)row * N + col] = f2bs(v);
        }
      }
}

// ---------------------------------------------------------------------------
// Combined projection dispatch: KV projection (1024 blocks) + Q projection
// (132 blocks) in one launch (both only depend on their LN'd inputs).
//   bid < KVBLK : A=kv_ln, BT=[WkT;WvT], epilogues -> swizzled Kh / Vh
//   else        : A=q_ln,  BT=WqT,      epilogue  -> Qbuf (bias, bf16)
// ---------------------------------------------------------------------------
__global__ __launch_bounds__(256) void gemm_proj(
    const u16* __restrict__ Akv, const u16* __restrict__ Aq,
    const u16* __restrict__ WTbase, const float* __restrict__ biasK,
    const float* __restrict__ biasV, const float* __restrict__ biasQ,
    u16* __restrict__ Kh, u16* __restrict__ Vh, u16* __restrict__ Qb) {
  __shared__ short As[64][40];
  __shared__ short Bs[64][40];
  __shared__ u16 Ct[64][72];
  int bid = blockIdx.x;
  int tid = threadIdx.x;
  int lane = tid & 63, w = tid >> 6;
  int g = lane >> 4, li = lane & 15;
  int wr = w >> 1, wc = w & 1;
  f32x4 acc[2][2] = {};
  const long DD = (long)D * D;

  bool isKV = bid < KVBLK;
  int bm, bn, M;
  const u16* A;
  const u16* BT;
  if (isKV) {
    bn = (bid & 7) * 64;
    bm = (bid >> 3) * 64;
    M = KVROWS;
    A = Akv;
    BT = WTbase;  // rows 0..511 = [WkT; WvT]
  } else {
    int qb = bid - KVBLK;
    bn = (qb & 3) * 64;
    bm = (qb >> 2) * 64;
    M = QROWS;
    A = Aq;
    BT = WTbase + 2 * DD;  // WqT
  }

  int srow = tid >> 2, skc = (tid & 3) * 8;
  for (int k0 = 0; k0 < D; k0 += 32) {
    {
      int grow = bm + srow;
      bf16x8 av = {};
      if (grow < M)
        av = *reinterpret_cast<const bf16x8*>(A + (long)grow * D + k0 + skc);
      *reinterpret_cast<bf16x8*>(&As[srow][skc]) = av;
      bf16x8 bv = *reinterpret_cast<const bf16x8*>(
          BT + (long)(bn + srow) * D + k0 + skc);
      *reinterpret_cast<bf16x8*>(&Bs[srow][skc]) = bv;
    }
    __syncthreads();
    bf16x8 a0 = *reinterpret_cast<const bf16x8*>(&As[wr * 32 + li][g * 8]);
    bf16x8 a1 = *reinterpret_cast<const bf16x8*>(&As[wr * 32 + 16 + li][g * 8]);
    bf16x8 b0 = *reinterpret_cast<const bf16x8*>(&Bs[wc * 32 + li][g * 8]);
    bf16x8 b1 = *reinterpret_cast<const bf16x8*>(&Bs[wc * 32 + 16 + li][g * 8]);
    acc[0][0] = __builtin_amdgcn_mfma_f32_16x16x32_bf16(a0, b0, acc[0][0], 0, 0, 0);
    acc[0][1] = __builtin_amdgcn_mfma_f32_16x16x32_bf16(a0, b1, acc[0][1], 0, 0, 0);
    acc[1][0] = __builtin_amdgcn_mfma_f32_16x16x32_bf16(a1, b0, acc[1][0], 0, 0, 0);
    acc[1][1] = __builtin_amdgcn_mfma_f32_16x16x32_bf16(a1, b1, acc[1][1], 0, 0, 0);
    __syncthreads();
  }

  if (!isKV) {
    // Q epilogue: bias -> bf16 [row][col]
#pragma unroll
    for (int mr = 0; mr < 2; ++mr)
#pragma unroll
      for (int nr = 0; nr < 2; ++nr)
#pragma unroll
        for (int r = 0; r < 4; ++r) {
          int row = bm + wr * 32 + mr * 16 + g * 4 + r;
          int col = bn + wc * 32 + nr * 16 + li;
          if (row >= M) continue;
          Qb[(long)row * D + col] = f2bs(acc[mr][nr][r] + biasQ[col]);
        }
  } else if (bn < 256) {
    // K epilogue: Kh[b][h][key][dchunk ^ ((key>>1)&3)]
#pragma unroll
    for (int mr = 0; mr < 2; ++mr)
#pragma unroll
      for (int nr = 0; nr < 2; ++nr)
#pragma unroll
        for (int r = 0; r < 4; ++r) {
          int rowL = wr * 32 + mr * 16 + g * 4 + r;
          int colL = wc * 32 + nr * 16 + li;
          Ct[rowL][colL] = f2bs(acc[mr][nr][r] + biasK[bn + colL]);
        }
    __syncthreads();
#pragma unroll
    for (int p = 0; p < 2; ++p) {
      int rowL = (tid >> 3) + p * 32;
      int c8 = (tid & 7) * 8;
      int grow = bm + rowL;
      int b2 = grow >> 12, key = grow & (L - 1);
      int gcol = bn + c8;
      int hh = gcol >> 5, dd = gcol & (HD - 1);
      int cst = (dd >> 3) ^ ((key >> 1) & 3);
      u16* dst = Kh + (((long)(b2 * H + hh) * L + key) * 32 + (cst << 3));
      *reinterpret_cast<bf16x8*>(dst) =
          *reinterpret_cast<const bf16x8*>(&Ct[rowL][c8]);
    }
  } else {
    // V epilogue: Vh[b][h][key/32][d][kchunk ^ ((d>>1)&6)]
    int vbn = bn - 256;
#pragma unroll
    for (int mr = 0; mr < 2; ++mr)
#pragma unroll
      for (int nr = 0; nr < 2; ++nr)
#pragma unroll
        for (int r = 0; r < 4; ++r) {
          int rowL = wr * 32 + mr * 16 + g * 4 + r;
          int colL = wc * 32 + nr * 16 + li;
          Ct[colL][rowL] = f2bs(acc[mr][nr][r] + biasV[vbn + colL]);
        }
    __syncthreads();
    int b2 = bm >> 12;
#pragma unroll
    for (int p = 0; p < 2; ++p) {
      int colL = (tid >> 3) + p * 32;
      int rem = tid & 7;
      int kb = rem >> 2, k8 = (rem & 3) * 8;
      int gcol = vbn + colL;
      int hh = gcol >> 5, dd = gcol & (HD - 1);
      int kb32 = ((bm & (L - 1)) >> 5) + kb;
      int j = (k8 >> 2) ^ ((dd >> 1) & 6);
      u16* dst = Vh + (((long)(b2 * H + hh) * (L / 32) + kb32) * 1024 +
                       dd * 32 + (j << 2));
      *reinterpret_cast<bf16x8*>(dst) =
          *reinterpret_cast<const bf16x8*>(&Ct[colL][kb * 32 + k8]);
    }
  }
}

// ---------------------------------------------------------------------------
// Fused flash attention: 512 threads = 8 split-K waves per (b,h,32-q tile).
// Single 4KB wave-private LDS buffer via global_load_lds DMA; per-iteration
// issue -> vmcnt(0) -> compute, latency hidden by TLP (34KB LDS -> up to
// 4 blocks/CU = 32 waves/CU). Kh/Vh XOR-swizzled in global (conflict-free
// reads). No-max exp2 softmax -> plain-sum split-K combine. XCD swizzle.
// ---------------------------------------------------------------------------
constexpr int POOLSZ = NSPLIT * 32 * 33 * 4 + NSPLIT * 32 * 4;  // 34816

__global__ __launch_bounds__(512) void attn_mfma(
    const u16* __restrict__ Qb, const u16* __restrict__ Kh,
    const u16* __restrict__ Vh, u16* __restrict__ AO) {
  __shared__ alignas(16) char pool[POOLSZ];
  int i = blockIdx.x;
  int xcd = i & 7, slot = i >> 3;          // 66 slots per XCD
  int bh = (xcd << 1) | (slot >= NQT ? 1 : 0);
  int qt = (slot >= NQT) ? slot - NQT : slot;
  int h = bh & 7;
  int b = bh >> 3;
  int tid = threadIdx.x, w = tid >> 6, lane = tid & 63;
  int g = lane >> 4, li = lane & 15;

  fr qf0, qf1;
  {
    const float QSC = 0.25509836048f;  // (1/sqrt(32)) * log2(e)
#pragma unroll
    for (int qb = 0; qb < 2; ++qb) {
      int qrow = qt * 32 + qb * 16 + li;
      if (qrow >= Q_MAX) qrow = Q_MAX - 1;
      bf16x8 raw = *reinterpret_cast<const bf16x8*>(
          Qb + ((long)(b * Q_MAX + qrow)) * D + h * HD + g * 8);
      fr& qf = qb ? qf1 : qf0;
#pragma unroll
      for (int j = 0; j < 4; ++j)
        qf.i[j] = (int)cvt_pk(bs2f((u16)raw[2 * j]) * QSC,
                              bs2f((u16)raw[2 * j + 1]) * QSC);
    }
  }

  f32x4 acc00 = {}, acc01 = {}, acc10 = {}, acc11 = {};
  float den0 = 0.f, den1 = 0.f;
  const f32x4 z = {};

  const u16* kbase = Kh + ((long)(b * H + h) * L) * HD;
  const u16* vbase = Vh + ((long)(b * H + h) * L) * HD;
  int kstart = w * KCHUNK;
  char* wbase = pool + w * 4096;  // wave-private single buffer (2KB K + 2KB V)

  // swizzled LDS read offsets (u16 units)
  int s_li = (li >> 1) & 3;
  int t_li = (li >> 1) & 6;
  int kof0 = li * 32 + ((g ^ s_li) << 3);
  int kof1 = (16 + li) * 32 + ((g ^ s_li) << 3);
  int va0o = li * 32 + ((g ^ t_li) << 2);
  int vb0o = li * 32 + (((4 + g) ^ t_li) << 2);
  int va1o = (16 + li) * 32 + ((g ^ t_li) << 2);
  int vb1o = (16 + li) * 32 + (((4 + g) ^ t_li) << 2);

  for (int t = 0; t < NT; ++t) {
    {
      const u16* ks = kbase + (long)(kstart + t * 32) * HD + lane * 8;
      const u16* vs = vbase + (long)(kstart + t * 32) * HD + lane * 8;
      u16* lk = (u16*)wbase;
      // prior iter's LDS reads must complete before DMA overwrites buffer
      asm volatile("s_waitcnt lgkmcnt(0)" ::: "memory");
      GLL16(ks, lk);
      GLL16(ks + 512, lk + 512);
      GLL16(vs, lk + 1024);
      GLL16(vs + 512, lk + 1536);
      asm volatile("s_waitcnt vmcnt(0)" ::: "memory");
      __builtin_amdgcn_sched_barrier(0);
    }

    const u16* kl = (const u16*)wbase;
    const u16* vl = kl + 1024;
    bf16x8 kf0 = *reinterpret_cast<const bf16x8*>(kl + kof0);
    bf16x8 kf1 = *reinterpret_cast<const bf16x8*>(kl + kof1);
    uint2 va0 = *reinterpret_cast<const uint2*>(vl + va0o);
    uint2 vb0 = *reinterpret_cast<const uint2*>(vl + vb0o);
    uint2 va1 = *reinterpret_cast<const uint2*>(vl + va1o);
    uint2 vb1 = *reinterpret_cast<const uint2*>(vl + vb1o);

    f32x4 s00 = __builtin_amdgcn_mfma_f32_16x16x32_bf16(kf0, qf0.h, z, 0, 0, 0);
    f32x4 s10 = __builtin_amdgcn_mfma_f32_16x16x32_bf16(kf1, qf0.h, z, 0, 0, 0);
    f32x4 s01 = __builtin_amdgcn_mfma_f32_16x16x32_bf16(kf0, qf1.h, z, 0, 0, 0);
    f32x4 s11 = __builtin_amdgcn_mfma_f32_16x16x32_bf16(kf1, qf1.h, z, 0, 0, 0);

    float p00[4], p10[4], p01[4], p11[4];
#pragma unroll
    for (int r = 0; r < 4; ++r) {
      p00[r] = exp2f(s00[r]);
      p10[r] = exp2f(s10[r]);
      p01[r] = exp2f(s01[r]);
      p11[r] = exp2f(s11[r]);
      den0 += p00[r] + p10[r];
      den1 += p01[r] + p11[r];
    }
    fr pf0, pf1;
    pf0.i[0] = (int)cvt_pk(p00[0], p00[1]);
    pf0.i[1] = (int)cvt_pk(p00[2], p00[3]);
    pf0.i[2] = (int)cvt_pk(p10[0], p10[1]);
    pf0.i[3] = (int)cvt_pk(p10[2], p10[3]);
    pf1.i[0] = (int)cvt_pk(p01[0], p01[1]);
    pf1.i[1] = (int)cvt_pk(p01[2], p01[3]);
    pf1.i[2] = (int)cvt_pk(p11[0], p11[1]);
    pf1.i[3] = (int)cvt_pk(p11[2], p11[3]);

    fr v0, v1;
    v0.i = (i32x4){(int)va0.x, (int)va0.y, (int)vb0.x, (int)vb0.y};
    v1.i = (i32x4){(int)va1.x, (int)va1.y, (int)vb1.x, (int)vb1.y};
    acc00 = __builtin_amdgcn_mfma_f32_16x16x32_bf16(v0.h, pf0.h, acc00, 0, 0, 0);
    acc01 = __builtin_amdgcn_mfma_f32_16x16x32_bf16(v0.h, pf1.h, acc01, 0, 0, 0);
    acc10 = __builtin_amdgcn_mfma_f32_16x16x32_bf16(v1.h, pf0.h, acc10, 0, 0, 0);
    acc11 = __builtin_amdgcn_mfma_f32_16x16x32_bf16(v1.h, pf1.h, acc11, 0, 0, 0);
  }

  // reduce per-lane denominators over g
  den0 += __shfl_xor(den0, 16, 64);
  den0 += __shfl_xor(den0, 32, 64);
  den1 += __shfl_xor(den1, 16, 64);
  den1 += __shfl_xor(den1, 32, 64);

  // combine: overlay staging LDS (all waves done with it after barrier)
  __syncthreads();
  float (*accs)[32][33] = (float(*)[32][33])pool;
  float (*dsh)[32] = (float(*)[32])(pool + NSPLIT * 32 * 33 * 4);
#pragma unroll
  for (int r = 0; r < 4; ++r) {
    accs[w][g * 4 + r][li] = acc00[r];
    accs[w][g * 4 + r][16 + li] = acc01[r];
    accs[w][16 + g * 4 + r][li] = acc10[r];
    accs[w][16 + g * 4 + r][16 + li] = acc11[r];
  }
  if (g == 0) {
    dsh[w][li] = den0;
    dsh[w][16 + li] = den1;
  }
  __syncthreads();

  int q = tid >> 4, dp = tid & 15;  // q 0..31, d-pair 0..15
  float Den = 0.f, o0 = 0.f, o1 = 0.f;
#pragma unroll
  for (int ww = 0; ww < NSPLIT; ++ww) {
    Den += dsh[ww][q];
    o0 += accs[ww][2 * dp][q];
    o1 += accs[ww][2 * dp + 1][q];
  }
  float inv = 1.f / Den;
  int qrow = qt * 32 + q;
  if (qrow < Q_MAX) {
    unsigned pk = cvt_pk(o0 * inv, o1 * inv);
    *reinterpret_cast<unsigned*>(
        AO + ((long)(b * Q_MAX + qrow)) * D + h * HD + 2 * dp) = pk;
  }
}

// ---------------------------------------------------------------------------
__global__ __launch_bounds__(256) void head_kernel(
    const float* __restrict__ enc, const float* __restrict__ hW,
    const float* __restrict__ hb, float* __restrict__ out) {
  int row = blockIdx.x * 4 + (threadIdx.x >> 6);
  int lane = threadIdx.x & 63;
  const float4 a = *reinterpret_cast<const float4*>(enc + (long)row * D + lane * 4);
  float c0 = 0.f, c1 = 0.f, c2 = 0.f;
  const float av[4] = {a.x, a.y, a.z, a.w};
#pragma unroll
  for (int i = 0; i < 4; ++i) {
    int k = lane * 4 + i;
    c0 += av[i] * hW[k * 3];
    c1 += av[i] * hW[k * 3 + 1];
    c2 += av[i] * hW[k * 3 + 2];
  }
#pragma unroll
  for (int off = 32; off; off >>= 1) {
    c0 += __shfl_down(c0, off, 64);
    c1 += __shfl_down(c1, off, 64);
    c2 += __shfl_down(c2, off, 64);
  }
  if (lane == 0) {
    out[(long)row * 3] = c0 + hb[0];
    out[(long)row * 3 + 1] = c1 + hb[1];
    out[(long)row * 3 + 2] = c2 + hb[2];
  }
}

// ---------------------------------------------------------------------------
__global__ __launch_bounds__(64) void overwrite_kernel(
    const float* __restrict__ q_stream, const int* __restrict__ idx,
    const int* __restrict__ mask, const float* __restrict__ hW,
    const float* __restrict__ hb, float* __restrict__ out) {
  int j = blockIdx.x;
  if (!mask[j]) return;
  int b = j / Q_MAX;
  int p = idx[j];
  int lane = threadIdx.x;
  const float* a = q_stream + (long)j * D;
  float a0 = a[lane], a1 = a[lane + 64], a2 = a[lane + 128],
        a3 = a[lane + 192];
  for (int c = 0; c < 3; ++c) {
    float s = a0 * hW[lane * 3 + c] + a1 * hW[(lane + 64) * 3 + c] +
              a2 * hW[(lane + 128) * 3 + c] + a3 * hW[(lane + 192) * 3 + c];
    for (int off = 32; off > 0; off >>= 1) s += __shfl_down(s, off, 64);
    if (lane == 0) out[((long)b * L + p) * 3 + c] = s + hb[c];
  }
}

// ---------------------------------------------------------------------------
extern "C" void kernel_launch(void* const* d_in, const int* in_sizes, int n_in,
                              void* d_out, int out_size, void* d_ws,
                              size_t ws_size, hipStream_t stream) {
  const float* enc = (const float*)d_in[0];
  const float* clog = (const float*)d_in[1];
  const float* ln_q_g = (const float*)d_in[2];
  const float* ln_q_b = (const float*)d_in[3];
  const float* ln_kv_g = (const float*)d_in[4];
  const float* ln_kv_b = (const float*)d_in[5];
  const float* Wq = (const float*)d_in[6];
  const float* bq = (const float*)d_in[7];
  const float* Wk = (const float*)d_in[8];
  const float* bk = (const float*)d_in[9];
  const float* Wv = (const float*)d_in[10];
  const float* bv = (const float*)d_in[11];
  const float* Wo = (const float*)d_in[12];
  const float* bo = (const float*)d_in[13];
  const float* ffn_g = (const float*)d_in[14];
  const float* ffn_b = (const float*)d_in[15];
  const float* W1 = (const float*)d_in[16];
  const float* b1 = (const float*)d_in[17];
  const float* W2 = (const float*)d_in[18];
  const float* b2 = (const float*)d_in[19];
  const float* head_W = (const float*)d_in[20];
  const float* head_b = (const float*)d_in[21];
  float* out = (float*)d_out;

  char* ws = (char*)d_ws;
  float* q_stream = (float*)ws;            ws += (long)QROWS * D * 4;
  u16* kvl0 = (u16*)ws;                    ws += (long)KVROWS * D * 2;
  u16* kvl1 = (u16*)ws;                    ws += (long)KVROWS * D * 2;
  u16* Khbuf = (u16*)ws;                   ws += (long)B * H * L * HD * 2;
  u16* Vhbuf = (u16*)ws;                   ws += (long)B * H * L * HD * 2;
  u16* q_ln = (u16*)ws;                    ws += (long)QROWS * D * 2;
  u16* Qbuf = (u16*)ws;                    ws += (long)QROWS * D * 2;
  u16* AObuf = (u16*)ws;                   ws += (long)QROWS * D * 2;
  u16* H1buf = (u16*)ws;                   ws += (long)QROWS * FF * 2;
  u16* WT = (u16*)ws;                      ws += (long)NL * (4 * D * D + 2 * D * FF) * 2;
  int* idxbuf = (int*)ws;                  ws += QROWS * 4;
  int* maskbuf = (int*)ws;

  const long DD = (long)D * D, DFF = (long)D * FF;
  const long LSTR = 4 * DD + 2 * DFF;

  transpose_tiled<<<NL * 192, 256, 0, stream>>>(Wq, Wk, Wv, Wo, W1, W2, WT);
  ln_kv2<<<KVROWS, 256, 0, stream>>>(enc, kvl0, kvl1, ln_kv_g, ln_kv_b);
  select_kernel<<<B, 1024, 0, stream>>>(clog, idxbuf, maskbuf);
  gather_kernel<<<QROWS, 256, 0, stream>>>(enc, idxbuf, q_stream);

  for (int l = 0; l < NL; ++l) {
    u16* base = WT + l * LSTR;
    u16* kv_ln = (l == 0) ? kvl0 : kvl1;

    ln_bf16<<<QROWS, 256, 0, stream>>>(q_stream, q_ln, ln_q_g + l * D, ln_q_b + l * D);

    gemm_proj<<<KVBLK + QBLK, 256, 0, stream>>>(
        kv_ln, q_ln, base, bk + l * D, bv + l * D, bq + l * D, Khbuf, Vhbuf,
        Qbuf);

    attn_mfma<<<B * H * NQT, 512, 0, stream>>>(Qbuf, Khbuf, Vhbuf, AObuf);

    dim3 gQ(D / 64, (QROWS + 63) / 64);
    gemm_mfma<2><<<gQ, 256, 0, stream>>>(AObuf, base + 3 * DD, bo + l * D,
                                         (void*)q_stream, q_stream, maskbuf,
                                         QROWS, D, D);

    ln_bf16<<<QROWS, 256, 0, stream>>>(q_stream, q_ln, ffn_g + l * D, ffn_b + l * D);
    dim3 gF1(FF / 64, (QROWS + 63) / 64);
    gemm_mfma<1><<<gF1, 256, 0, stream>>>(q_ln, base + 4 * DD, b1 + l * FF,
                                          (void*)H1buf, nullptr, nullptr,
                                          QROWS, FF, D);
    dim3 gF2(D / 64, (QROWS + 63) / 64);
    gemm_mfma<2><<<gF2, 256, 0, stream>>>(H1buf, base + 4 * DD + DFF,
                                          b2 + l * D, (void*)q_stream,
                                          q_stream, maskbuf, QROWS, D, FF);
  }

  head_kernel<<<KVROWS / 4, 256, 0, stream>>>(enc, head_W, head_b, out);
  overwrite_kernel<<<QROWS, 64, 0, stream>>>(q_stream, idxbuf, maskbuf, head_W,
                                             head_b, out);
}